// Round 11
// baseline (241.777 us; speedup 1.0000x reference)
//
#include <hip/hip_runtime.h>
#include <hip/hip_bf16.h>
#include <cfloat>

#define NN 100000
#define EE 1000000
#define TE (EE + NN)   // edges incl. self loops
#define C1 128         // HEADS*HID
#define C2 64
#define NB1 782        // ceil(NN/128)
#define NBKT 782       // buckets of 128 dst nodes
#define BCAP 4096      // per-bucket edge capacity (expected ~1280)

typedef unsigned short u16;
typedef unsigned int u32;
using bf16x8 = __attribute__((ext_vector_type(8))) short;
using f32x4  = __attribute__((ext_vector_type(4))) float;

__device__ __forceinline__ float lrelu(float v) { return v > 0.f ? v : 0.2f * v; }
__device__ __forceinline__ u16 f2bf(float f) {           // RNE f32 -> bf16 bits
    u32 b = __float_as_uint(f);
    b += 0x7fffu + ((b >> 16) & 1u);
    return (u16)(b >> 16);
}
__device__ __forceinline__ float bflo(u32 p) { return __uint_as_float(p << 16); }
__device__ __forceinline__ float bfhi(u32 p) { return __uint_as_float(p & 0xffff0000u); }

// ==== precompute: W2pbt = (W2@fcW)^T bf16, W1bt = W1^T bf16, us/ud, b2p ====
__global__ __launch_bounds__(64) void kprep(const float* __restrict__ W2,
    const float* __restrict__ as2, const float* __restrict__ ad2,
    const float* __restrict__ b2, const float* __restrict__ fcW,
    const float* __restrict__ fcb, const float* __restrict__ W1,
    u16* __restrict__ W2pbt, u16* __restrict__ W1bt,
    float* __restrict__ us, float* __restrict__ ud, float* __restrict__ b2p) {
    int b = blockIdx.x, t = threadIdx.x;
    if (b < 128) {                     // row b of W2p -> transposed bf16
        float s = 0.f;
        for (int k = 0; k < 64; ++k) s = fmaf(W2[b * 64 + k], fcW[k * 64 + t], s);
        W2pbt[t * 128 + b] = f2bf(s);
    } else if (b < 130) {
        int r = (b - 128) * 64 + t;
        float s = 0.f, d = 0.f;
        for (int k = 0; k < 64; ++k) {
            float wv = W2[r * 64 + k];
            s = fmaf(wv, as2[k], s);
            d = fmaf(wv, ad2[k], d);
        }
        us[r] = s; ud[r] = d;
    } else if (b == 130) {
        float s = fcb[t];
        for (int k = 0; k < 64; ++k) s = fmaf(b2[k], fcW[k * 64 + t], s);
        b2p[t] = s;
    } else {                           // b-131 = col c of W1 -> W1bt[c][k]
        int c = b - 131;
        W1bt[c * 128 + t]      = f2bf(W1[t * 128 + c]);
        W1bt[c * 128 + 64 + t] = f2bf(W1[(64 + t) * 128 + c]);
    }
}

// ========== CSR build, bucketed (2 passes; no random-line HBM traffic) ==========
__global__ __launch_bounds__(256) void kpassA(const int* __restrict__ esrc,
    const int* __restrict__ edst, int* __restrict__ bcnt, u32* __restrict__ bbuf) {
    int i = blockIdx.x * 256 + threadIdx.x;
    if (i >= EE / 4) return;
    int4 s4 = ((const int4*)esrc)[i];
    int4 d4 = ((const int4*)edst)[i];
    int d, s, b, pos;
    d = d4.x; s = s4.x; b = d >> 7;
    pos = atomicAdd(bcnt + b * 16, 1);
    if (pos < BCAP) bbuf[(size_t)b * BCAP + pos] = (u32)s | ((u32)(d & 127) << 17);
    d = d4.y; s = s4.y; b = d >> 7;
    pos = atomicAdd(bcnt + b * 16, 1);
    if (pos < BCAP) bbuf[(size_t)b * BCAP + pos] = (u32)s | ((u32)(d & 127) << 17);
    d = d4.z; s = s4.z; b = d >> 7;
    pos = atomicAdd(bcnt + b * 16, 1);
    if (pos < BCAP) bbuf[(size_t)b * BCAP + pos] = (u32)s | ((u32)(d & 127) << 17);
    d = d4.w; s = s4.w; b = d >> 7;
    pos = atomicAdd(bcnt + b * 16, 1);
    if (pos < BCAP) bbuf[(size_t)b * BCAP + pos] = (u32)s | ((u32)(d & 127) << 17);
}

__global__ __launch_bounds__(1024) void kbscan(const int* __restrict__ bcnt,
                                               int* __restrict__ bbase) {
    __shared__ int sm[1024];
    int t = threadIdx.x;
    int v = 0;
    if (t < NBKT) {
        int node0 = t * 128;
        int nn = NN - node0; if (nn > 128) nn = 128;
        int m = bcnt[t * 16]; if (m > BCAP) m = BCAP;
        v = m + nn;
    }
    sm[t] = v;
    __syncthreads();
    for (int off = 1; off < 1024; off <<= 1) {
        int o = 0;
        if (t >= off) o = sm[t - off];
        __syncthreads();
        if (t >= off) sm[t] += o;
        __syncthreads();
    }
    if (t < NBKT) bbase[t] = sm[t] - v;
}

__global__ __launch_bounds__(256) void kpassB(const int* __restrict__ bcnt,
    const int* __restrict__ bbase, const u32* __restrict__ bbuf,
    int* __restrict__ rowstart, int* __restrict__ eidx) {
    __shared__ int deg[128], lsc[128], cur[128];
    __shared__ int elocal[BCAP + 128];
    int b = blockIdx.x, t = threadIdx.x;
    int node0 = b * 128;
    int nNodes = NN - node0; if (nNodes > 128) nNodes = 128;
    int M = bcnt[b * 16]; if (M > BCAP) M = BCAP;
    int base = bbase[b];
    if (t < 128) deg[t] = 0;
    __syncthreads();
    const u32* bp = bbuf + (size_t)b * BCAP;
    for (int i = t; i < M; i += 256) atomicAdd(&deg[bp[i] >> 17], 1);
    __syncthreads();
    int v = 0;
    if (t < 128) { v = (t < nNodes) ? (1 + deg[t]) : 0; lsc[t] = v; }
    __syncthreads();
    for (int off = 1; off < 128; off <<= 1) {
        int o = 0;
        if (t < 128 && t >= off) o = lsc[t - off];
        __syncthreads();
        if (t < 128 && t >= off) lsc[t] += o;
        __syncthreads();
    }
    if (t < nNodes) {
        int st = lsc[t] - v;              // exclusive
        rowstart[node0 + t] = base + st;
        elocal[st] = node0 + t;           // self loop in slot 0
        cur[t] = st + 1;
    }
    if (b == NBKT - 1 && t == 0) rowstart[NN] = TE;
    __syncthreads();
    for (int i = t; i < M; i += 256) {
        u32 p = bp[i];
        int pos = atomicAdd(&cur[p >> 17], 1);
        elocal[pos] = (int)(p & 0x1FFFFu);
    }
    __syncthreads();
    int total = M + nNodes;
    for (int i = t; i < total; i += 256) eidx[base + i] = elocal[i];
}

// ============ GEMM1 (MFMA): h1 = x @ W1, 128x128x128 per block ============
__global__ __launch_bounds__(256, 1) void k1_mfma(const float* __restrict__ x,
    const u16* __restrict__ W1bt, u16* __restrict__ h1b) {
    __shared__ u16 As[128][136];   // A[row][k], +8 pad
    __shared__ u16 Bs[128][136];   // B^T: [col][k]
    int t = threadIdx.x;
    int rbase = blockIdx.x * 128;
    #pragma unroll
    for (int j = 0; j < 8; ++j) {          // stage W1^T (bf16, linear)
        int i = t + 256 * j, row = i >> 4, seg = i & 15;
        *reinterpret_cast<uint4*>(&Bs[row][seg * 8]) =
            *reinterpret_cast<const uint4*>(W1bt + row * 128 + seg * 8);
    }
    #pragma unroll
    for (int j = 0; j < 16; ++j) {         // stage x tile, fp32->bf16
        int i = t + 256 * j, row = i >> 5, c4 = i & 31;
        int gr = rbase + row; if (gr >= NN) gr = NN - 1;
        float4 v = *reinterpret_cast<const float4*>(x + (size_t)gr * 128 + c4 * 4);
        ushort4 o2 = make_ushort4(f2bf(v.x), f2bf(v.y), f2bf(v.z), f2bf(v.w));
        *reinterpret_cast<ushort4*>(&As[row][c4 * 4]) = o2;
    }
    __syncthreads();
    int lane = t & 63, wv = t >> 6, wr = wv >> 1, wc = wv & 1;
    int fr = lane & 15, fg = lane >> 4;
    f32x4 acc[4][4];
    #pragma unroll
    for (int m = 0; m < 4; ++m)
        #pragma unroll
        for (int n = 0; n < 4; ++n) acc[m][n] = (f32x4){0.f, 0.f, 0.f, 0.f};
    #pragma unroll
    for (int kk = 0; kk < 4; ++kk) {
        bf16x8 af[4], bfr[4];
        #pragma unroll
        for (int m = 0; m < 4; ++m)
            af[m] = *reinterpret_cast<const bf16x8*>(&As[wr * 64 + m * 16 + fr][kk * 32 + fg * 8]);
        #pragma unroll
        for (int n = 0; n < 4; ++n)
            bfr[n] = *reinterpret_cast<const bf16x8*>(&Bs[wc * 64 + n * 16 + fr][kk * 32 + fg * 8]);
        #pragma unroll
        for (int m = 0; m < 4; ++m)
            #pragma unroll
            for (int n = 0; n < 4; ++n)
                acc[m][n] = __builtin_amdgcn_mfma_f32_16x16x32_bf16(af[m], bfr[n], acc[m][n], 0, 0, 0);
    }
    #pragma unroll
    for (int m = 0; m < 4; ++m)
        #pragma unroll
        for (int r = 0; r < 4; ++r) {
            int row = rbase + wr * 64 + m * 16 + fg * 4 + r;
            if (row < NN) {
                #pragma unroll
                for (int n = 0; n < 4; ++n)
                    h1b[(size_t)row * 128 + wc * 64 + n * 16 + fr] = f2bf(acc[m][n][r]);
            }
        }
}

// ====== Aggregation layer 1: scores computed in-register from gathered rows ======
// lane: channels 4c..4c+3 (c=lane&31), head hh=c>>3; edges of parity half=lane>>5.
// Online softmax over 16-edge batches; no score arrays, no kscore kernel.
__global__ __launch_bounds__(256) void agg1(const int* __restrict__ rowstart,
    const int* __restrict__ eidx, const u16* __restrict__ h1b,
    const float* __restrict__ as1, const float* __restrict__ ad1,
    const float* __restrict__ b1, const float* __restrict__ usv,
    const float* __restrict__ udv, u16* __restrict__ hrb,
    float* __restrict__ ssrc2, float* __restrict__ sdst2) {
    int lane = threadIdx.x & 63;
    int n = blockIdx.x * 4 + (threadIdx.x >> 6);
    if (n >= NN) return;
    int half = lane >> 5, c = lane & 31, j16 = lane & 15;
    // self row (no eidx dependency -> issues immediately) -> dst score
    uint2 sfr = *(const uint2*)(h1b + (size_t)n * C1 + 4 * c);
    float4 asv = *(const float4*)(as1 + 4 * c);
    float4 adv = *(const float4*)(ad1 + 4 * c);
    int r0 = rowstart[n], deg = rowstart[n + 1] - r0;
    float pdh = bflo(sfr.x) * adv.x + bfhi(sfr.x) * adv.y
              + bflo(sfr.y) * adv.z + bfhi(sfr.y) * adv.w;
    pdh += __shfl_xor(pdh, 1); pdh += __shfl_xor(pdh, 2); pdh += __shfl_xor(pdh, 4);
    // online softmax + accumulate
    float m = -FLT_MAX, den = 0.f, a0 = 0.f, a1 = 0.f, a2 = 0.f, a3 = 0.f;
    for (int base = 0; base < deg; base += 16) {
        int sj = (base + j16 < deg) ? eidx[r0 + base + j16] : eidx[r0];
        uint2 pv[8];
        #pragma unroll
        for (int q = 0; q < 8; ++q) {
            int s = __shfl(sj, 2 * q + half);
            pv[q] = *(const uint2*)(h1b + (size_t)s * C1 + 4 * c);
        }
        float x0[8], x1[8], x2[8], x3[8], e[8];
        #pragma unroll
        for (int q = 0; q < 8; ++q) {
            x0[q] = bflo(pv[q].x); x1[q] = bfhi(pv[q].x);
            x2[q] = bflo(pv[q].y); x3[q] = bfhi(pv[q].y);
            float p = x0[q] * asv.x + x1[q] * asv.y + x2[q] * asv.z + x3[q] * asv.w;
            p += __shfl_xor(p, 1); p += __shfl_xor(p, 2); p += __shfl_xor(p, 4);
            e[q] = (base + 2 * q + half < deg) ? lrelu(p + pdh) : -FLT_MAX;
        }
        float bm = e[0];
        #pragma unroll
        for (int q = 1; q < 8; ++q) bm = fmaxf(bm, e[q]);
        bm = fmaxf(bm, __shfl_xor(bm, 32));
        float mn = fmaxf(m, bm);
        float rr = __expf(m - mn);         // first batch: exp(-inf)=0, acc/den are 0
        a0 *= rr; a1 *= rr; a2 *= rr; a3 *= rr; den *= rr;
        m = mn;
        #pragma unroll
        for (int q = 0; q < 8; ++q) {
            float w = __expf(e[q] - m);
            den += w;
            a0 = fmaf(w, x0[q], a0);
            a1 = fmaf(w, x1[q], a1);
            a2 = fmaf(w, x2[q], a2);
            a3 = fmaf(w, x3[q], a3);
        }
    }
    // combine edge parities (m is group-uniform, so exp scales match)
    den += __shfl_xor(den, 32);
    a0 += __shfl_xor(a0, 32);
    a1 += __shfl_xor(a1, 32);
    a2 += __shfl_xor(a2, 32);
    a3 += __shfl_xor(a3, 32);
    float4 bv = *(const float4*)(b1 + 4 * c);
    float rv = 1.f / den;
    float v0 = fmaf(a0, rv, bv.x); v0 = v0 > 0.f ? v0 : 0.f;
    float v1 = fmaf(a1, rv, bv.y); v1 = v1 > 0.f ? v1 : 0.f;
    float v2 = fmaf(a2, rv, bv.z); v2 = v2 > 0.f ? v2 : 0.f;
    float v3 = fmaf(a3, rv, bv.w); v3 = v3 > 0.f ? v3 : 0.f;
    // layer-2 scores: dot(relu_h, us/ud) over 128 channels (32-lane reduce)
    float4 u_s = *(const float4*)(usv + 4 * c);
    float4 u_d = *(const float4*)(udv + 4 * c);
    float ps = v0 * u_s.x + v1 * u_s.y + v2 * u_s.z + v3 * u_s.w;
    float pd = v0 * u_d.x + v1 * u_d.y + v2 * u_d.z + v3 * u_d.w;
    #pragma unroll
    for (int off = 1; off <= 16; off <<= 1) {
        ps += __shfl_xor(ps, off); pd += __shfl_xor(pd, off);
    }
    if (lane == 0) { ssrc2[n] = ps; sdst2[n] = pd; }
    if (half == 0) {
        ushort4 hs = make_ushort4(f2bf(v0), f2bf(v1), f2bf(v2), f2bf(v3));
        *reinterpret_cast<ushort4*>(hrb + (size_t)n * C1 + 4 * c) = hs;
    }
}

// ============ GEMM2 (MFMA): h3 = hrb @ (W2@fcW), 128x64x128 per block ============
__global__ __launch_bounds__(256, 1) void k5_mfma(const u16* __restrict__ hrb,
    const u16* __restrict__ W2pbt, u16* __restrict__ h3b) {
    __shared__ u16 As[128][136];
    __shared__ u16 Bs[64][136];
    int t = threadIdx.x;
    int rbase = blockIdx.x * 128;
    #pragma unroll
    for (int j = 0; j < 4; ++j) {          // stage (W2@fcW)^T bf16
        int i = t + 256 * j, row = i >> 4, seg = i & 15;
        *reinterpret_cast<uint4*>(&Bs[row][seg * 8]) =
            *reinterpret_cast<const uint4*>(W2pbt + row * 128 + seg * 8);
    }
    #pragma unroll
    for (int j = 0; j < 8; ++j) {          // stage hrb tile (bf16, linear)
        int i = t + 256 * j, row = i >> 4, seg = i & 15;
        int gr = rbase + row; if (gr >= NN) gr = NN - 1;
        *reinterpret_cast<uint4*>(&As[row][seg * 8]) =
            *reinterpret_cast<const uint4*>(hrb + (size_t)gr * 128 + seg * 8);
    }
    __syncthreads();
    int lane = t & 63, wv = t >> 6, wr = wv >> 1, wc = wv & 1;
    int fr = lane & 15, fg = lane >> 4;
    f32x4 acc[4][2];
    #pragma unroll
    for (int m = 0; m < 4; ++m)
        #pragma unroll
        for (int n = 0; n < 2; ++n) acc[m][n] = (f32x4){0.f, 0.f, 0.f, 0.f};
    #pragma unroll
    for (int kk = 0; kk < 4; ++kk) {
        bf16x8 af[4], bfr[2];
        #pragma unroll
        for (int m = 0; m < 4; ++m)
            af[m] = *reinterpret_cast<const bf16x8*>(&As[wr * 64 + m * 16 + fr][kk * 32 + fg * 8]);
        #pragma unroll
        for (int n = 0; n < 2; ++n)
            bfr[n] = *reinterpret_cast<const bf16x8*>(&Bs[wc * 32 + n * 16 + fr][kk * 32 + fg * 8]);
        #pragma unroll
        for (int m = 0; m < 4; ++m)
            #pragma unroll
            for (int n = 0; n < 2; ++n)
                acc[m][n] = __builtin_amdgcn_mfma_f32_16x16x32_bf16(af[m], bfr[n], acc[m][n], 0, 0, 0);
    }
    #pragma unroll
    for (int m = 0; m < 4; ++m)
        #pragma unroll
        for (int r = 0; r < 4; ++r) {
            int row = rbase + wr * 64 + m * 16 + fg * 4 + r;
            if (row < NN) {
                #pragma unroll
                for (int n = 0; n < 2; ++n)
                    h3b[(size_t)row * 64 + wc * 32 + n * 16 + fr] = f2bf(acc[m][n][r]);
            }
        }
}

// ====== Aggregation layer 2 + log_softmax (FC pre-folded into h3) ======
__global__ __launch_bounds__(256) void agg2ls(const int* __restrict__ rowstart,
    const int* __restrict__ eidx, const float* __restrict__ ssrc,
    const float* __restrict__ sdst, const u16* __restrict__ h3b,
    const float* __restrict__ b2p, float* __restrict__ out) {
    int lane = threadIdx.x & 63;
    int n = blockIdx.x * 4 + (threadIdx.x >> 6);
    if (n >= NN) return;
    int r0 = rowstart[n], deg = rowstart[n + 1] - r0;
    int j16 = lane & 15, quarter = lane >> 4, c16 = lane & 15;
    float sd = sdst[n];
    int s0 = (j16 < deg) ? eidx[r0 + j16] : eidx[r0];
    uint2 pv[4];
    #pragma unroll
    for (int q = 0; q < 4; ++q) {
        int s = __shfl(s0, 4 * q + quarter);
        pv[q] = *(const uint2*)(h3b + (size_t)s * C2 + 4 * c16);
    }
    float sv0 = (j16 < deg) ? lrelu(ssrc[s0] + sd) : -FLT_MAX;
    float mx = sv0;
    #pragma unroll
    for (int off = 1; off <= 8; off <<= 1) mx = fmaxf(mx, __shfl_xor(mx, off));
    for (int base = 16; base < deg; base += 16) {            // rare
        int j = base + j16;
        float sv = (j < deg) ? lrelu(ssrc[eidx[r0 + j]] + sd) : -FLT_MAX;
        #pragma unroll
        for (int off = 1; off <= 8; off <<= 1) sv = fmaxf(sv, __shfl_xor(sv, off));
        mx = fmaxf(mx, sv);
    }
    float w = (j16 < deg) ? __expf(sv0 - mx) : 0.f;
    float den = w;
    float a0 = 0.f, a1 = 0.f, a2 = 0.f, a3 = 0.f;
    #pragma unroll
    for (int q = 0; q < 4; ++q) {
        float wq = __shfl(w, 4 * q + quarter);
        a0 = fmaf(wq, bflo(pv[q].x), a0);
        a1 = fmaf(wq, bfhi(pv[q].x), a1);
        a2 = fmaf(wq, bflo(pv[q].y), a2);
        a3 = fmaf(wq, bfhi(pv[q].y), a3);
    }
    for (int base = 16; base < deg; base += 16) {            // rare
        int j = base + j16;
        int sreg = (j < deg) ? eidx[r0 + j] : eidx[r0];
        uint2 qv[4];
        #pragma unroll
        for (int q = 0; q < 4; ++q) {
            int s = __shfl(sreg, 4 * q + quarter);
            qv[q] = *(const uint2*)(h3b + (size_t)s * C2 + 4 * c16);
        }
        float wb = (j < deg) ? __expf(lrelu(ssrc[sreg] + sd) - mx) : 0.f;
        den += wb;
        #pragma unroll
        for (int q = 0; q < 4; ++q) {
            float wq = __shfl(wb, 4 * q + quarter);
            a0 = fmaf(wq, bflo(qv[q].x), a0);
            a1 = fmaf(wq, bfhi(qv[q].x), a1);
            a2 = fmaf(wq, bflo(qv[q].y), a2);
            a3 = fmaf(wq, bfhi(qv[q].y), a3);
        }
    }
    #pragma unroll
    for (int off = 1; off <= 8; off <<= 1) den += __shfl_xor(den, off);
    a0 += __shfl_xor(a0, 16); a0 += __shfl_xor(a0, 32);
    a1 += __shfl_xor(a1, 16); a1 += __shfl_xor(a1, 32);
    a2 += __shfl_xor(a2, 16); a2 += __shfl_xor(a2, 32);
    a3 += __shfl_xor(a3, 16); a3 += __shfl_xor(a3, 32);
    float4 bv = *(const float4*)(b2p + 4 * c16);
    float rd = 1.f / den;
    float v0 = a0 * rd + bv.x, v1 = a1 * rd + bv.y;
    float v2 = a2 * rd + bv.z, v3 = a3 * rd + bv.w;
    float m4 = fmaxf(fmaxf(v0, v1), fmaxf(v2, v3));
    #pragma unroll
    for (int off = 1; off <= 8; off <<= 1) m4 = fmaxf(m4, __shfl_xor(m4, off));
    float se = __expf(v0 - m4) + __expf(v1 - m4) + __expf(v2 - m4) + __expf(v3 - m4);
    #pragma unroll
    for (int off = 1; off <= 8; off <<= 1) se += __shfl_xor(se, off);
    float lse = m4 + logf(se);
    if (quarter == 0) {
        *(float4*)(out + (size_t)n * C2 + 4 * c16) =
            make_float4(v0 - lse, v1 - lse, v2 - lse, v3 - lse);
    }
}

extern "C" void kernel_launch(void* const* d_in, const int* in_sizes, int n_in,
                              void* d_out, int out_size, void* d_ws, size_t ws_size,
                              hipStream_t stream) {
    const float* x   = (const float*)d_in[0];
    const int*   ei  = (const int*)d_in[1];
    const float* W1  = (const float*)d_in[2];
    const float* as1 = (const float*)d_in[3];
    const float* ad1 = (const float*)d_in[4];
    const float* b1  = (const float*)d_in[5];
    const float* W2  = (const float*)d_in[6];
    const float* as2 = (const float*)d_in[7];
    const float* ad2 = (const float*)d_in[8];
    const float* b2  = (const float*)d_in[9];
    const float* fcW = (const float*)d_in[10];
    const float* fcb = (const float*)d_in[11];
    float* out = (float*)d_out;

    float* ws = (float*)d_ws;
    size_t o = 0;
    u16* h1b   = (u16*)(ws + o); o += (size_t)NN * C1 / 2;  // bf16 [NN][128] (reused as h3b)
    u16* hrb   = (u16*)(ws + o); o += (size_t)NN * C1 / 2;  // bf16 [NN][128]
    float* ssrc2 = ws + o; o += NN;
    float* sdst2 = ws + o; o += NN;
    float* usv   = ws + o; o += 128;
    float* udv   = ws + o; o += 128;
    float* b2p   = ws + o; o += 64;
    u16* W2pbt = (u16*)(ws + o); o += 64 * 128 / 2;
    u16* W1bt  = (u16*)(ws + o); o += 128 * 128 / 2;
    int* ip = (int*)(ws + o);
    int* bcnt     = ip; ip += NBKT * 16;       // line-padded counters
    int* bbase    = ip; ip += 1024;
    int* rowstart = ip; ip += NN + 2;
    int* eidx     = ip; ip += TE;
    u32* bbuf     = (u32*)ip; ip += (size_t)NBKT * BCAP;   // 12.8 MB
    u16* h3b = h1b;   // h1b dead after agg1; reuse for h3

    const int* esrc = ei;
    const int* edst = ei + EE;

    hipMemsetAsync(bcnt, 0, (size_t)NBKT * 16 * sizeof(int), stream);

    // fold FC into layer-2 weights; bf16-transposed weight copies
    kprep<<<259, 64, 0, stream>>>(W2, as2, ad2, b2, fcW, fcb, W1,
                                  W2pbt, W1bt, usv, udv, b2p);

    // CSR build, bucketed
    kpassA<<<(EE / 4 + 255) / 256, 256, 0, stream>>>(esrc, edst, bcnt, bbuf);
    kbscan<<<1, 1024, 0, stream>>>(bcnt, bbase);
    kpassB<<<NBKT, 256, 0, stream>>>(bcnt, bbase, bbuf, rowstart, eidx);

    // layer 1
    k1_mfma<<<NB1, 256, 0, stream>>>(x, W1bt, h1b);
    agg1<<<(NN + 3) / 4, 256, 0, stream>>>(rowstart, eidx, h1b, as1, ad1, b1,
                                           usv, udv, hrb, ssrc2, sdst2);
    // layer 2 (FC pre-folded)
    k5_mfma<<<NB1, 256, 0, stream>>>(hrb, W2pbt, h3b);
    agg2ls<<<(NN + 3) / 4, 256, 0, stream>>>(rowstart, eidx, ssrc2, sdst2, h3b, b2p, out);
}

// Round 12
// 216.244 us; speedup vs baseline: 1.1181x; 1.1181x over previous
//
#include <hip/hip_runtime.h>
#include <hip/hip_bf16.h>
#include <cfloat>

#define NN 100000
#define EE 1000000
#define TE (EE + NN)   // edges incl. self loops
#define C1 128         // HEADS*HID
#define C2 64
#define NB1 782        // ceil(NN/128)
#define NBKT 782       // buckets of 128 dst nodes
#define BCAP 4096      // per-bucket edge capacity (expected ~1280)

typedef unsigned short u16;
typedef unsigned int u32;
using bf16x8 = __attribute__((ext_vector_type(8))) short;
using f32x4  = __attribute__((ext_vector_type(4))) float;

__device__ __forceinline__ float lrelu(float v) { return v > 0.f ? v : 0.2f * v; }
__device__ __forceinline__ u16 f2bf(float f) {           // RNE f32 -> bf16 bits
    u32 b = __float_as_uint(f);
    b += 0x7fffu + ((b >> 16) & 1u);
    return (u16)(b >> 16);
}
__device__ __forceinline__ float bflo(u32 p) { return __uint_as_float(p << 16); }
__device__ __forceinline__ float bfhi(u32 p) { return __uint_as_float(p & 0xffff0000u); }

// ==== precompute: W2pbt = (W2@fcW)^T bf16, W1bt = W1^T bf16, us/ud, b2p ====
__global__ __launch_bounds__(64) void kprep(const float* __restrict__ W2,
    const float* __restrict__ as2, const float* __restrict__ ad2,
    const float* __restrict__ b2, const float* __restrict__ fcW,
    const float* __restrict__ fcb, const float* __restrict__ W1,
    u16* __restrict__ W2pbt, u16* __restrict__ W1bt,
    float* __restrict__ us, float* __restrict__ ud, float* __restrict__ b2p) {
    int b = blockIdx.x, t = threadIdx.x;
    if (b < 128) {                     // row b of W2p -> transposed bf16
        float s = 0.f;
        for (int k = 0; k < 64; ++k) s = fmaf(W2[b * 64 + k], fcW[k * 64 + t], s);
        W2pbt[t * 128 + b] = f2bf(s);
    } else if (b < 130) {
        int r = (b - 128) * 64 + t;
        float s = 0.f, d = 0.f;
        for (int k = 0; k < 64; ++k) {
            float wv = W2[r * 64 + k];
            s = fmaf(wv, as2[k], s);
            d = fmaf(wv, ad2[k], d);
        }
        us[r] = s; ud[r] = d;
    } else if (b == 130) {
        float s = fcb[t];
        for (int k = 0; k < 64; ++k) s = fmaf(b2[k], fcW[k * 64 + t], s);
        b2p[t] = s;
    } else {                           // b-131 = col c of W1 -> W1bt[c][k]
        int c = b - 131;
        W1bt[c * 128 + t]      = f2bf(W1[t * 128 + c]);
        W1bt[c * 128 + 64 + t] = f2bf(W1[(64 + t) * 128 + c]);
    }
}

// ========== CSR build, bucketed (2 passes; no random-line HBM traffic) ==========
__global__ __launch_bounds__(256) void kpassA(const int* __restrict__ esrc,
    const int* __restrict__ edst, int* __restrict__ bcnt, u32* __restrict__ bbuf) {
    int i = blockIdx.x * 256 + threadIdx.x;
    if (i >= EE / 4) return;
    int4 s4 = ((const int4*)esrc)[i];
    int4 d4 = ((const int4*)edst)[i];
    int d, s, b, pos;
    d = d4.x; s = s4.x; b = d >> 7;
    pos = atomicAdd(bcnt + b * 16, 1);
    if (pos < BCAP) bbuf[(size_t)b * BCAP + pos] = (u32)s | ((u32)(d & 127) << 17);
    d = d4.y; s = s4.y; b = d >> 7;
    pos = atomicAdd(bcnt + b * 16, 1);
    if (pos < BCAP) bbuf[(size_t)b * BCAP + pos] = (u32)s | ((u32)(d & 127) << 17);
    d = d4.z; s = s4.z; b = d >> 7;
    pos = atomicAdd(bcnt + b * 16, 1);
    if (pos < BCAP) bbuf[(size_t)b * BCAP + pos] = (u32)s | ((u32)(d & 127) << 17);
    d = d4.w; s = s4.w; b = d >> 7;
    pos = atomicAdd(bcnt + b * 16, 1);
    if (pos < BCAP) bbuf[(size_t)b * BCAP + pos] = (u32)s | ((u32)(d & 127) << 17);
}

__global__ __launch_bounds__(1024) void kbscan(const int* __restrict__ bcnt,
                                               int* __restrict__ bbase) {
    __shared__ int sm[1024];
    int t = threadIdx.x;
    int v = 0;
    if (t < NBKT) {
        int node0 = t * 128;
        int nn = NN - node0; if (nn > 128) nn = 128;
        int m = bcnt[t * 16]; if (m > BCAP) m = BCAP;
        v = m + nn;
    }
    sm[t] = v;
    __syncthreads();
    for (int off = 1; off < 1024; off <<= 1) {
        int o = 0;
        if (t >= off) o = sm[t - off];
        __syncthreads();
        if (t >= off) sm[t] += o;
        __syncthreads();
    }
    if (t < NBKT) bbase[t] = sm[t] - v;
}

__global__ __launch_bounds__(256) void kpassB(const int* __restrict__ bcnt,
    const int* __restrict__ bbase, const u32* __restrict__ bbuf,
    int* __restrict__ rowstart, int* __restrict__ eidx) {
    __shared__ int deg[128], lsc[128], cur[128];
    __shared__ int elocal[BCAP + 128];
    int b = blockIdx.x, t = threadIdx.x;
    int node0 = b * 128;
    int nNodes = NN - node0; if (nNodes > 128) nNodes = 128;
    int M = bcnt[b * 16]; if (M > BCAP) M = BCAP;
    int base = bbase[b];
    if (t < 128) deg[t] = 0;
    __syncthreads();
    const u32* bp = bbuf + (size_t)b * BCAP;
    for (int i = t; i < M; i += 256) atomicAdd(&deg[bp[i] >> 17], 1);
    __syncthreads();
    int v = 0;
    if (t < 128) { v = (t < nNodes) ? (1 + deg[t]) : 0; lsc[t] = v; }
    __syncthreads();
    for (int off = 1; off < 128; off <<= 1) {
        int o = 0;
        if (t < 128 && t >= off) o = lsc[t - off];
        __syncthreads();
        if (t < 128 && t >= off) lsc[t] += o;
        __syncthreads();
    }
    if (t < nNodes) {
        int st = lsc[t] - v;              // exclusive
        rowstart[node0 + t] = base + st;
        elocal[st] = node0 + t;           // self loop in slot 0
        cur[t] = st + 1;
    }
    if (b == NBKT - 1 && t == 0) rowstart[NN] = TE;
    __syncthreads();
    for (int i = t; i < M; i += 256) {
        u32 p = bp[i];
        int pos = atomicAdd(&cur[p >> 17], 1);
        elocal[pos] = (int)(p & 0x1FFFFu);
    }
    __syncthreads();
    int total = M + nNodes;
    for (int i = t; i < total; i += 256) eidx[base + i] = elocal[i];
}

// ============ GEMM1 (MFMA): h1 = x @ W1 + fused layer-1 scores ============
// 4 waves: wave (wr,wc) owns 64x64 quadrant; scores from acc regs in epilogue.
__global__ __launch_bounds__(256, 1) void k1_mfma(const float* __restrict__ x,
    const u16* __restrict__ W1bt, const float* __restrict__ as1,
    const float* __restrict__ ad1, u16* __restrict__ h1b,
    float* __restrict__ ssrc, float* __restrict__ sdst) {
    __shared__ u16 As[128][136];   // A[row][k], +8 pad
    __shared__ u16 Bs[128][136];   // B^T: [col][k]
    int t = threadIdx.x;
    int rbase = blockIdx.x * 128;
    #pragma unroll
    for (int j = 0; j < 8; ++j) {          // stage W1^T (bf16, linear)
        int i = t + 256 * j, row = i >> 4, seg = i & 15;
        *reinterpret_cast<uint4*>(&Bs[row][seg * 8]) =
            *reinterpret_cast<const uint4*>(W1bt + row * 128 + seg * 8);
    }
    #pragma unroll
    for (int j = 0; j < 16; ++j) {         // stage x tile, fp32->bf16
        int i = t + 256 * j, row = i >> 5, c4 = i & 31;
        int gr = rbase + row; if (gr >= NN) gr = NN - 1;
        float4 v = *reinterpret_cast<const float4*>(x + (size_t)gr * 128 + c4 * 4);
        ushort4 o2 = make_ushort4(f2bf(v.x), f2bf(v.y), f2bf(v.z), f2bf(v.w));
        *reinterpret_cast<ushort4*>(&As[row][c4 * 4]) = o2;
    }
    __syncthreads();
    int lane = t & 63, wv = t >> 6, wr = wv >> 1, wc = wv & 1;
    int fr = lane & 15, fg = lane >> 4;
    f32x4 acc[4][4];
    #pragma unroll
    for (int m = 0; m < 4; ++m)
        #pragma unroll
        for (int n = 0; n < 4; ++n) acc[m][n] = (f32x4){0.f, 0.f, 0.f, 0.f};
    #pragma unroll
    for (int kk = 0; kk < 4; ++kk) {
        bf16x8 af[4], bfr[4];
        #pragma unroll
        for (int m = 0; m < 4; ++m)
            af[m] = *reinterpret_cast<const bf16x8*>(&As[wr * 64 + m * 16 + fr][kk * 32 + fg * 8]);
        #pragma unroll
        for (int n = 0; n < 4; ++n)
            bfr[n] = *reinterpret_cast<const bf16x8*>(&Bs[wc * 64 + n * 16 + fr][kk * 32 + fg * 8]);
        #pragma unroll
        for (int m = 0; m < 4; ++m)
            #pragma unroll
            for (int n = 0; n < 4; ++n)
                acc[m][n] = __builtin_amdgcn_mfma_f32_16x16x32_bf16(af[m], bfr[n], acc[m][n], 0, 0, 0);
    }
    // per-lane score vectors: col = wc*64 + n*16 + fr
    float asv[4], adv[4];
    #pragma unroll
    for (int n = 0; n < 4; ++n) {
        int col = wc * 64 + n * 16 + fr;
        asv[n] = as1[col]; adv[n] = ad1[col];
    }
    #pragma unroll
    for (int m = 0; m < 4; ++m)
        #pragma unroll
        for (int r = 0; r < 4; ++r) {
            int row = rbase + wr * 64 + m * 16 + fg * 4 + r;
            bool ok = row < NN;
            if (ok) {
                #pragma unroll
                for (int n = 0; n < 4; ++n)
                    h1b[(size_t)row * 128 + wc * 64 + n * 16 + fr] = f2bf(acc[m][n][r]);
            }
            // fused scores: heads 2wc (n=0,1) and 2wc+1 (n=2,3)
            float psA = acc[m][0][r] * asv[0] + acc[m][1][r] * asv[1];
            float psB = acc[m][2][r] * asv[2] + acc[m][3][r] * asv[3];
            float pdA = acc[m][0][r] * adv[0] + acc[m][1][r] * adv[1];
            float pdB = acc[m][2][r] * adv[2] + acc[m][3][r] * adv[3];
            #pragma unroll
            for (int off = 1; off <= 8; off <<= 1) {
                psA += __shfl_xor(psA, off); psB += __shfl_xor(psB, off);
                pdA += __shfl_xor(pdA, off); pdB += __shfl_xor(pdB, off);
            }
            if (fr == 0 && ok) {
                ssrc[row * 4 + 2 * wc]     = psA; sdst[row * 4 + 2 * wc]     = pdA;
                ssrc[row * 4 + 2 * wc + 1] = psB; sdst[row * 4 + 2 * wc + 1] = pdB;
            }
        }
}

// ====== Aggregation layer 1 + layer-2 scores; writes bf16 hrb (R10 structure) ======
__global__ __launch_bounds__(256) void agg1(const int* __restrict__ rowstart,
    const int* __restrict__ eidx, const float* __restrict__ ssrc,
    const float* __restrict__ sdst, const u16* __restrict__ h1b,
    const float* __restrict__ b1, const float* __restrict__ usv,
    const float* __restrict__ udv, u16* __restrict__ hrb,
    float* __restrict__ ssrc2, float* __restrict__ sdst2) {
    int lane = threadIdx.x & 63;
    int n = blockIdx.x * 4 + (threadIdx.x >> 6);
    if (n >= NN) return;
    int r0 = rowstart[n], deg = rowstart[n + 1] - r0;
    int h4 = lane >> 4, j16 = lane & 15;
    int half = lane >> 5, c = lane & 31, hh = c >> 3;
    float sd = sdst[n * 4 + h4];
    int s0 = (j16 < deg) ? eidx[r0 + j16] : eidx[r0];
    uint2 pv[8];
    #pragma unroll
    for (int q = 0; q < 8; ++q) {
        int s = __shfl(s0, 2 * q + half);
        pv[q] = *(const uint2*)(h1b + (size_t)s * C1 + 4 * c);
    }
    float sv0 = (j16 < deg) ? lrelu(ssrc[s0 * 4 + h4] + sd) : -FLT_MAX;
    float mx = sv0;
    #pragma unroll
    for (int off = 1; off <= 8; off <<= 1) mx = fmaxf(mx, __shfl_xor(mx, off));
    for (int base = 16; base < deg; base += 16) {            // rare (deg>16)
        int j = base + j16;
        float sv = (j < deg) ? lrelu(ssrc[eidx[r0 + j] * 4 + h4] + sd) : -FLT_MAX;
        #pragma unroll
        for (int off = 1; off <= 8; off <<= 1) sv = fmaxf(sv, __shfl_xor(sv, off));
        mx = fmaxf(mx, sv);
    }
    float w = (j16 < deg) ? __expf(sv0 - mx) : 0.f;
    float den = w;
    float a0 = 0.f, a1 = 0.f, a2 = 0.f, a3 = 0.f;
    #pragma unroll
    for (int q = 0; q < 8; ++q) {
        float wq = __shfl(w, (hh << 4) + 2 * q + half);
        a0 = fmaf(wq, bflo(pv[q].x), a0);
        a1 = fmaf(wq, bfhi(pv[q].x), a1);
        a2 = fmaf(wq, bflo(pv[q].y), a2);
        a3 = fmaf(wq, bfhi(pv[q].y), a3);
    }
    for (int base = 16; base < deg; base += 16) {            // rare (deg>16)
        int j = base + j16;
        int sreg = (j < deg) ? eidx[r0 + j] : eidx[r0];
        uint2 qv[8];
        #pragma unroll
        for (int q = 0; q < 8; ++q) {
            int s = __shfl(sreg, 2 * q + half);
            qv[q] = *(const uint2*)(h1b + (size_t)s * C1 + 4 * c);
        }
        float wb = (j < deg) ? __expf(lrelu(ssrc[sreg * 4 + h4] + sd) - mx) : 0.f;
        den += wb;
        #pragma unroll
        for (int q = 0; q < 8; ++q) {
            float wq = __shfl(wb, (hh << 4) + 2 * q + half);
            a0 = fmaf(wq, bflo(qv[q].x), a0);
            a1 = fmaf(wq, bfhi(qv[q].x), a1);
            a2 = fmaf(wq, bflo(qv[q].y), a2);
            a3 = fmaf(wq, bfhi(qv[q].y), a3);
        }
    }
    #pragma unroll
    for (int off = 1; off <= 8; off <<= 1) den += __shfl_xor(den, off);
    float dh = __shfl(den, hh << 4);
    a0 += __shfl_xor(a0, 32);
    a1 += __shfl_xor(a1, 32);
    a2 += __shfl_xor(a2, 32);
    a3 += __shfl_xor(a3, 32);
    float4 bv = *(const float4*)(b1 + 4 * c);
    float rv = 1.f / dh;
    float v0 = fmaf(a0, rv, bv.x); v0 = v0 > 0.f ? v0 : 0.f;
    float v1 = fmaf(a1, rv, bv.y); v1 = v1 > 0.f ? v1 : 0.f;
    float v2 = fmaf(a2, rv, bv.z); v2 = v2 > 0.f ? v2 : 0.f;
    float v3 = fmaf(a3, rv, bv.w); v3 = v3 > 0.f ? v3 : 0.f;
    // layer-2 scores: dot(relu_h, us/ud) over 128 channels (32-lane reduce)
    float4 u_s = *(const float4*)(usv + 4 * c);
    float4 u_d = *(const float4*)(udv + 4 * c);
    float ps = v0 * u_s.x + v1 * u_s.y + v2 * u_s.z + v3 * u_s.w;
    float pd = v0 * u_d.x + v1 * u_d.y + v2 * u_d.z + v3 * u_d.w;
    #pragma unroll
    for (int off = 1; off <= 16; off <<= 1) {
        ps += __shfl_xor(ps, off); pd += __shfl_xor(pd, off);
    }
    if (lane == 0) { ssrc2[n] = ps; sdst2[n] = pd; }
    if (half == 0) {
        ushort4 hs = make_ushort4(f2bf(v0), f2bf(v1), f2bf(v2), f2bf(v3));
        *reinterpret_cast<ushort4*>(hrb + (size_t)n * C1 + 4 * c) = hs;
    }
}

// ============ GEMM2 (MFMA): h3 = hrb @ (W2@fcW), 128x64x128 per block ============
__global__ __launch_bounds__(256, 1) void k5_mfma(const u16* __restrict__ hrb,
    const u16* __restrict__ W2pbt, u16* __restrict__ h3b) {
    __shared__ u16 As[128][136];
    __shared__ u16 Bs[64][136];
    int t = threadIdx.x;
    int rbase = blockIdx.x * 128;
    #pragma unroll
    for (int j = 0; j < 4; ++j) {          // stage (W2@fcW)^T bf16
        int i = t + 256 * j, row = i >> 4, seg = i & 15;
        *reinterpret_cast<uint4*>(&Bs[row][seg * 8]) =
            *reinterpret_cast<const uint4*>(W2pbt + row * 128 + seg * 8);
    }
    #pragma unroll
    for (int j = 0; j < 8; ++j) {          // stage hrb tile (bf16, linear)
        int i = t + 256 * j, row = i >> 4, seg = i & 15;
        int gr = rbase + row; if (gr >= NN) gr = NN - 1;
        *reinterpret_cast<uint4*>(&As[row][seg * 8]) =
            *reinterpret_cast<const uint4*>(hrb + (size_t)gr * 128 + seg * 8);
    }
    __syncthreads();
    int lane = t & 63, wv = t >> 6, wr = wv >> 1, wc = wv & 1;
    int fr = lane & 15, fg = lane >> 4;
    f32x4 acc[4][2];
    #pragma unroll
    for (int m = 0; m < 4; ++m)
        #pragma unroll
        for (int n = 0; n < 2; ++n) acc[m][n] = (f32x4){0.f, 0.f, 0.f, 0.f};
    #pragma unroll
    for (int kk = 0; kk < 4; ++kk) {
        bf16x8 af[4], bfr[2];
        #pragma unroll
        for (int m = 0; m < 4; ++m)
            af[m] = *reinterpret_cast<const bf16x8*>(&As[wr * 64 + m * 16 + fr][kk * 32 + fg * 8]);
        #pragma unroll
        for (int n = 0; n < 2; ++n)
            bfr[n] = *reinterpret_cast<const bf16x8*>(&Bs[wc * 32 + n * 16 + fr][kk * 32 + fg * 8]);
        #pragma unroll
        for (int m = 0; m < 4; ++m)
            #pragma unroll
            for (int n = 0; n < 2; ++n)
                acc[m][n] = __builtin_amdgcn_mfma_f32_16x16x32_bf16(af[m], bfr[n], acc[m][n], 0, 0, 0);
    }
    #pragma unroll
    for (int m = 0; m < 4; ++m)
        #pragma unroll
        for (int r = 0; r < 4; ++r) {
            int row = rbase + wr * 64 + m * 16 + fg * 4 + r;
            if (row < NN) {
                #pragma unroll
                for (int n = 0; n < 2; ++n)
                    h3b[(size_t)row * 64 + wc * 32 + n * 16 + fr] = f2bf(acc[m][n][r]);
            }
        }
}

// ====== Aggregation layer 2 + log_softmax (FC pre-folded into h3) ======
__global__ __launch_bounds__(256) void agg2ls(const int* __restrict__ rowstart,
    const int* __restrict__ eidx, const float* __restrict__ ssrc,
    const float* __restrict__ sdst, const u16* __restrict__ h3b,
    const float* __restrict__ b2p, float* __restrict__ out) {
    int lane = threadIdx.x & 63;
    int n = blockIdx.x * 4 + (threadIdx.x >> 6);
    if (n >= NN) return;
    int r0 = rowstart[n], deg = rowstart[n + 1] - r0;
    int j16 = lane & 15, quarter = lane >> 4, c16 = lane & 15;
    float sd = sdst[n];
    int s0 = (j16 < deg) ? eidx[r0 + j16] : eidx[r0];
    uint2 pv[4];
    #pragma unroll
    for (int q = 0; q < 4; ++q) {
        int s = __shfl(s0, 4 * q + quarter);
        pv[q] = *(const uint2*)(h3b + (size_t)s * C2 + 4 * c16);
    }
    float sv0 = (j16 < deg) ? lrelu(ssrc[s0] + sd) : -FLT_MAX;
    float mx = sv0;
    #pragma unroll
    for (int off = 1; off <= 8; off <<= 1) mx = fmaxf(mx, __shfl_xor(mx, off));
    for (int base = 16; base < deg; base += 16) {            // rare
        int j = base + j16;
        float sv = (j < deg) ? lrelu(ssrc[eidx[r0 + j]] + sd) : -FLT_MAX;
        #pragma unroll
        for (int off = 1; off <= 8; off <<= 1) sv = fmaxf(sv, __shfl_xor(sv, off));
        mx = fmaxf(mx, sv);
    }
    float w = (j16 < deg) ? __expf(sv0 - mx) : 0.f;
    float den = w;
    float a0 = 0.f, a1 = 0.f, a2 = 0.f, a3 = 0.f;
    #pragma unroll
    for (int q = 0; q < 4; ++q) {
        float wq = __shfl(w, 4 * q + quarter);
        a0 = fmaf(wq, bflo(pv[q].x), a0);
        a1 = fmaf(wq, bfhi(pv[q].x), a1);
        a2 = fmaf(wq, bflo(pv[q].y), a2);
        a3 = fmaf(wq, bfhi(pv[q].y), a3);
    }
    for (int base = 16; base < deg; base += 16) {            // rare
        int j = base + j16;
        int sreg = (j < deg) ? eidx[r0 + j] : eidx[r0];
        uint2 qv[4];
        #pragma unroll
        for (int q = 0; q < 4; ++q) {
            int s = __shfl(sreg, 4 * q + quarter);
            qv[q] = *(const uint2*)(h3b + (size_t)s * C2 + 4 * c16);
        }
        float wb = (j < deg) ? __expf(lrelu(ssrc[sreg] + sd) - mx) : 0.f;
        den += wb;
        #pragma unroll
        for (int q = 0; q < 4; ++q) {
            float wq = __shfl(wb, 4 * q + quarter);
            a0 = fmaf(wq, bflo(qv[q].x), a0);
            a1 = fmaf(wq, bfhi(qv[q].x), a1);
            a2 = fmaf(wq, bflo(qv[q].y), a2);
            a3 = fmaf(wq, bfhi(qv[q].y), a3);
        }
    }
    #pragma unroll
    for (int off = 1; off <= 8; off <<= 1) den += __shfl_xor(den, off);
    a0 += __shfl_xor(a0, 16); a0 += __shfl_xor(a0, 32);
    a1 += __shfl_xor(a1, 16); a1 += __shfl_xor(a1, 32);
    a2 += __shfl_xor(a2, 16); a2 += __shfl_xor(a2, 32);
    a3 += __shfl_xor(a3, 16); a3 += __shfl_xor(a3, 32);
    float4 bv = *(const float4*)(b2p + 4 * c16);
    float rd = 1.f / den;
    float v0 = a0 * rd + bv.x, v1 = a1 * rd + bv.y;
    float v2 = a2 * rd + bv.z, v3 = a3 * rd + bv.w;
    float m4 = fmaxf(fmaxf(v0, v1), fmaxf(v2, v3));
    #pragma unroll
    for (int off = 1; off <= 8; off <<= 1) m4 = fmaxf(m4, __shfl_xor(m4, off));
    float se = __expf(v0 - m4) + __expf(v1 - m4) + __expf(v2 - m4) + __expf(v3 - m4);
    #pragma unroll
    for (int off = 1; off <= 8; off <<= 1) se += __shfl_xor(se, off);
    float lse = m4 + logf(se);
    if (quarter == 0) {
        *(float4*)(out + (size_t)n * C2 + 4 * c16) =
            make_float4(v0 - lse, v1 - lse, v2 - lse, v3 - lse);
    }
}

extern "C" void kernel_launch(void* const* d_in, const int* in_sizes, int n_in,
                              void* d_out, int out_size, void* d_ws, size_t ws_size,
                              hipStream_t stream) {
    const float* x   = (const float*)d_in[0];
    const int*   ei  = (const int*)d_in[1];
    const float* W1  = (const float*)d_in[2];
    const float* as1 = (const float*)d_in[3];
    const float* ad1 = (const float*)d_in[4];
    const float* b1  = (const float*)d_in[5];
    const float* W2  = (const float*)d_in[6];
    const float* as2 = (const float*)d_in[7];
    const float* ad2 = (const float*)d_in[8];
    const float* b2  = (const float*)d_in[9];
    const float* fcW = (const float*)d_in[10];
    const float* fcb = (const float*)d_in[11];
    float* out = (float*)d_out;

    float* ws = (float*)d_ws;
    size_t o = 0;
    u16* h1b   = (u16*)(ws + o); o += (size_t)NN * C1 / 2;  // bf16 [NN][128] (reused as h3b)
    u16* hrb   = (u16*)(ws + o); o += (size_t)NN * C1 / 2;  // bf16 [NN][128]
    float* ssrc1 = ws + o; o += (size_t)NN * 4;
    float* sdst1 = ws + o; o += (size_t)NN * 4;
    float* ssrc2 = ws + o; o += NN;
    float* sdst2 = ws + o; o += NN;
    float* usv   = ws + o; o += 128;
    float* udv   = ws + o; o += 128;
    float* b2p   = ws + o; o += 64;
    u16* W2pbt = (u16*)(ws + o); o += 64 * 128 / 2;
    u16* W1bt  = (u16*)(ws + o); o += 128 * 128 / 2;
    int* ip = (int*)(ws + o);
    int* bcnt     = ip; ip += NBKT * 16;       // line-padded counters
    int* bbase    = ip; ip += 1024;
    int* rowstart = ip; ip += NN + 2;
    int* eidx     = ip; ip += TE;
    u32* bbuf     = (u32*)ip; ip += (size_t)NBKT * BCAP;   // 12.8 MB
    u16* h3b = h1b;   // h1b dead after agg1; reuse for h3

    const int* esrc = ei;
    const int* edst = ei + EE;

    hipMemsetAsync(bcnt, 0, (size_t)NBKT * 16 * sizeof(int), stream);

    // fold FC into layer-2 weights; bf16-transposed weight copies
    kprep<<<259, 64, 0, stream>>>(W2, as2, ad2, b2, fcW, fcb, W1,
                                  W2pbt, W1bt, usv, udv, b2p);

    // CSR build, bucketed
    kpassA<<<(EE / 4 + 255) / 256, 256, 0, stream>>>(esrc, edst, bcnt, bbuf);
    kbscan<<<1, 1024, 0, stream>>>(bcnt, bbase);
    kpassB<<<NBKT, 256, 0, stream>>>(bcnt, bbase, bbuf, rowstart, eidx);

    // layer 1 (scores fused into GEMM epilogue)
    k1_mfma<<<NB1, 256, 0, stream>>>(x, W1bt, as1, ad1, h1b, ssrc1, sdst1);
    agg1<<<(NN + 3) / 4, 256, 0, stream>>>(rowstart, eidx, ssrc1, sdst1, h1b, b1,
                                           usv, udv, hrb, ssrc2, sdst2);
    // layer 2 (FC pre-folded)
    k5_mfma<<<NB1, 256, 0, stream>>>(hrb, W2pbt, h3b);
    agg2ls<<<(NN + 3) / 4, 256, 0, stream>>>(rowstart, eidx, ssrc2, sdst2, h3b, b2p, out);
}

// Round 13
// 216.084 us; speedup vs baseline: 1.1189x; 1.0007x over previous
//
#include <hip/hip_runtime.h>
#include <hip/hip_bf16.h>
#include <cfloat>

#define NN 100000
#define EE 1000000
#define TE (EE + NN)   // edges incl. self loops
#define C1 128         // HEADS*HID
#define C2 64
#define NB1 782        // ceil(NN/128)
#define NBKT 782       // buckets of 128 dst nodes
#define BCAP 4096      // per-bucket edge capacity (expected ~1280)
#define NPA 977        // ceil((EE/4)/256) edge-scatter blocks

typedef unsigned short u16;
typedef unsigned int u32;
using bf16x8 = __attribute__((ext_vector_type(8))) short;
using f32x4  = __attribute__((ext_vector_type(4))) float;

__device__ __forceinline__ float lrelu(float v) { return v > 0.f ? v : 0.2f * v; }
__device__ __forceinline__ u16 f2bf(float f) {           // RNE f32 -> bf16 bits
    u32 b = __float_as_uint(f);
    b += 0x7fffu + ((b >> 16) & 1u);
    return (u16)(b >> 16);
}
__device__ __forceinline__ float bflo(u32 p) { return __uint_as_float(p << 16); }
__device__ __forceinline__ float bfhi(u32 p) { return __uint_as_float(p & 0xffff0000u); }

// ====== merged: edge->bucket scatter (blocks < NPA) + weight precompute ======
__global__ __launch_bounds__(256) void kpassA(const int* __restrict__ esrc,
    const int* __restrict__ edst, int* __restrict__ bcnt, u32* __restrict__ bbuf,
    const float* __restrict__ W2, const float* __restrict__ as2,
    const float* __restrict__ ad2, const float* __restrict__ b2,
    const float* __restrict__ fcW, const float* __restrict__ fcb,
    const float* __restrict__ W1, u16* __restrict__ W2pbt, u16* __restrict__ W1bt,
    float* __restrict__ us, float* __restrict__ ud, float* __restrict__ b2p) {
    int blk = blockIdx.x;
    if (blk < NPA) {
        int i = blk * 256 + threadIdx.x;
        if (i >= EE / 4) return;
        int4 s4 = ((const int4*)esrc)[i];
        int4 d4 = ((const int4*)edst)[i];
        int d, s, b, pos;
        d = d4.x; s = s4.x; b = d >> 7;
        pos = atomicAdd(bcnt + b * 16, 1);
        if (pos < BCAP) bbuf[(size_t)b * BCAP + pos] = (u32)s | ((u32)(d & 127) << 17);
        d = d4.y; s = s4.y; b = d >> 7;
        pos = atomicAdd(bcnt + b * 16, 1);
        if (pos < BCAP) bbuf[(size_t)b * BCAP + pos] = (u32)s | ((u32)(d & 127) << 17);
        d = d4.z; s = s4.z; b = d >> 7;
        pos = atomicAdd(bcnt + b * 16, 1);
        if (pos < BCAP) bbuf[(size_t)b * BCAP + pos] = (u32)s | ((u32)(d & 127) << 17);
        d = d4.w; s = s4.w; b = d >> 7;
        pos = atomicAdd(bcnt + b * 16, 1);
        if (pos < BCAP) bbuf[(size_t)b * BCAP + pos] = (u32)s | ((u32)(d & 127) << 17);
        return;
    }
    // ---- prep role ----
    int b = blk - NPA, t = threadIdx.x;
    if (t >= 64) return;
    if (b < 128) {                     // row b of W2p -> transposed bf16
        float s = 0.f;
        for (int k = 0; k < 64; ++k) s = fmaf(W2[b * 64 + k], fcW[k * 64 + t], s);
        W2pbt[t * 128 + b] = f2bf(s);
    } else if (b < 130) {
        int r = (b - 128) * 64 + t;
        float s = 0.f, d = 0.f;
        for (int k = 0; k < 64; ++k) {
            float wv = W2[r * 64 + k];
            s = fmaf(wv, as2[k], s);
            d = fmaf(wv, ad2[k], d);
        }
        us[r] = s; ud[r] = d;
    } else if (b == 130) {
        float s = fcb[t];
        for (int k = 0; k < 64; ++k) s = fmaf(b2[k], fcW[k * 64 + t], s);
        b2p[t] = s;
    } else {                           // b-131 = col c of W1 -> W1bt[c][k]
        int c = b - 131;
        W1bt[c * 128 + t]      = f2bf(W1[t * 128 + c]);
        W1bt[c * 128 + 64 + t] = f2bf(W1[(64 + t) * 128 + c]);
    }
}

__global__ __launch_bounds__(1024) void kbscan(const int* __restrict__ bcnt,
                                               int* __restrict__ bbase) {
    __shared__ int sm[1024];
    int t = threadIdx.x;
    int v = 0;
    if (t < NBKT) {
        int node0 = t * 128;
        int nn = NN - node0; if (nn > 128) nn = 128;
        int m = bcnt[t * 16]; if (m > BCAP) m = BCAP;
        v = m + nn;
    }
    sm[t] = v;
    __syncthreads();
    for (int off = 1; off < 1024; off <<= 1) {
        int o = 0;
        if (t >= off) o = sm[t - off];
        __syncthreads();
        if (t >= off) sm[t] += o;
        __syncthreads();
    }
    if (t < NBKT) bbase[t] = sm[t] - v;
}

// ============ GEMM1 (MFMA): h1 = x @ W1 + fused layer-1 scores ============
__global__ __launch_bounds__(256, 1) void k1_mfma(const float* __restrict__ x,
    const u16* __restrict__ W1bt, const float* __restrict__ as1,
    const float* __restrict__ ad1, u16* __restrict__ h1b,
    float* __restrict__ ssrc, float* __restrict__ sdst) {
    __shared__ u16 As[128][136];   // A[row][k], +8 pad
    __shared__ u16 Bs[128][136];   // B^T: [col][k]
    int t = threadIdx.x;
    int rbase = blockIdx.x * 128;
    #pragma unroll
    for (int j = 0; j < 8; ++j) {          // stage W1^T (bf16, linear)
        int i = t + 256 * j, row = i >> 4, seg = i & 15;
        *reinterpret_cast<uint4*>(&Bs[row][seg * 8]) =
            *reinterpret_cast<const uint4*>(W1bt + row * 128 + seg * 8);
    }
    #pragma unroll
    for (int j = 0; j < 16; ++j) {         // stage x tile, fp32->bf16
        int i = t + 256 * j, row = i >> 5, c4 = i & 31;
        int gr = rbase + row; if (gr >= NN) gr = NN - 1;
        float4 v = *reinterpret_cast<const float4*>(x + (size_t)gr * 128 + c4 * 4);
        ushort4 o2 = make_ushort4(f2bf(v.x), f2bf(v.y), f2bf(v.z), f2bf(v.w));
        *reinterpret_cast<ushort4*>(&As[row][c4 * 4]) = o2;
    }
    __syncthreads();
    int lane = t & 63, wv = t >> 6, wr = wv >> 1, wc = wv & 1;
    int fr = lane & 15, fg = lane >> 4;
    f32x4 acc[4][4];
    #pragma unroll
    for (int m = 0; m < 4; ++m)
        #pragma unroll
        for (int n = 0; n < 4; ++n) acc[m][n] = (f32x4){0.f, 0.f, 0.f, 0.f};
    #pragma unroll
    for (int kk = 0; kk < 4; ++kk) {
        bf16x8 af[4], bfr[4];
        #pragma unroll
        for (int m = 0; m < 4; ++m)
            af[m] = *reinterpret_cast<const bf16x8*>(&As[wr * 64 + m * 16 + fr][kk * 32 + fg * 8]);
        #pragma unroll
        for (int n = 0; n < 4; ++n)
            bfr[n] = *reinterpret_cast<const bf16x8*>(&Bs[wc * 64 + n * 16 + fr][kk * 32 + fg * 8]);
        #pragma unroll
        for (int m = 0; m < 4; ++m)
            #pragma unroll
            for (int n = 0; n < 4; ++n)
                acc[m][n] = __builtin_amdgcn_mfma_f32_16x16x32_bf16(af[m], bfr[n], acc[m][n], 0, 0, 0);
    }
    float asv[4], adv[4];
    #pragma unroll
    for (int n = 0; n < 4; ++n) {
        int col = wc * 64 + n * 16 + fr;
        asv[n] = as1[col]; adv[n] = ad1[col];
    }
    #pragma unroll
    for (int m = 0; m < 4; ++m)
        #pragma unroll
        for (int r = 0; r < 4; ++r) {
            int row = rbase + wr * 64 + m * 16 + fg * 4 + r;
            bool ok = row < NN;
            if (ok) {
                #pragma unroll
                for (int n = 0; n < 4; ++n)
                    h1b[(size_t)row * 128 + wc * 64 + n * 16 + fr] = f2bf(acc[m][n][r]);
            }
            float psA = acc[m][0][r] * asv[0] + acc[m][1][r] * asv[1];
            float psB = acc[m][2][r] * asv[2] + acc[m][3][r] * asv[3];
            float pdA = acc[m][0][r] * adv[0] + acc[m][1][r] * adv[1];
            float pdB = acc[m][2][r] * adv[2] + acc[m][3][r] * adv[3];
            #pragma unroll
            for (int off = 1; off <= 8; off <<= 1) {
                psA += __shfl_xor(psA, off); psB += __shfl_xor(psB, off);
                pdA += __shfl_xor(pdA, off); pdB += __shfl_xor(pdB, off);
            }
            if (fr == 0 && ok) {
                ssrc[row * 4 + 2 * wc]     = psA; sdst[row * 4 + 2 * wc]     = pdA;
                ssrc[row * 4 + 2 * wc + 1] = psB; sdst[row * 4 + 2 * wc + 1] = pdB;
            }
        }
}

// ====== agg1 (bucket mode): in-LDS CSR finalize + aggregation + L2 scores ======
// Absorbs kpassB: per 128-node bucket, histogram/scan/scatter edges into LDS,
// emit rowstart/eidx for agg2ls, then aggregate with edge lists in LDS.
__global__ __launch_bounds__(256) void agg1(const int* __restrict__ bcnt,
    const int* __restrict__ bbase, const u32* __restrict__ bbuf,
    const float* __restrict__ ssrc, const float* __restrict__ sdst,
    const u16* __restrict__ h1b, const float* __restrict__ b1,
    const float* __restrict__ usv, const float* __restrict__ udv,
    u16* __restrict__ hrb, float* __restrict__ ssrc2, float* __restrict__ sdst2,
    int* __restrict__ rowstart, int* __restrict__ eidx) {
    __shared__ int deg[128], lsc[128], cur[128];
    __shared__ int elocal[BCAP + 128];
    int b = blockIdx.x, t = threadIdx.x;
    int node0 = b * 128;
    int nNodes = NN - node0; if (nNodes > 128) nNodes = 128;
    int M = bcnt[b * 16]; if (M > BCAP) M = BCAP;
    int base = bbase[b];
    if (t < 128) deg[t] = 0;
    __syncthreads();
    const u32* bp = bbuf + (size_t)b * BCAP;
    for (int i = t; i < M; i += 256) atomicAdd(&deg[bp[i] >> 17], 1);
    __syncthreads();
    int v = 0;
    if (t < 128) { v = (t < nNodes) ? (1 + deg[t]) : 0; lsc[t] = v; }
    __syncthreads();
    for (int off = 1; off < 128; off <<= 1) {
        int o = 0;
        if (t < 128 && t >= off) o = lsc[t - off];
        __syncthreads();
        if (t < 128 && t >= off) lsc[t] += o;
        __syncthreads();
    }
    if (t < nNodes) {
        int st = lsc[t] - v;              // exclusive
        rowstart[node0 + t] = base + st;
        elocal[st] = node0 + t;           // self loop in slot 0
        cur[t] = st + 1;
    }
    if (b == NBKT - 1 && t == 0) rowstart[NN] = TE;
    __syncthreads();
    for (int i = t; i < M; i += 256) {
        u32 p = bp[i];
        int pos = atomicAdd(&cur[p >> 17], 1);
        elocal[pos] = (int)(p & 0x1FFFFu);
    }
    __syncthreads();
    int total = M + nNodes;
    for (int i = t; i < total; i += 256) eidx[base + i] = elocal[i];  // for agg2ls
    __syncthreads();

    // ---- aggregation: wave wid handles nodes node0+wid, +4, +8, ... ----
    int lane = t & 63, wid = t >> 6;
    int h4 = lane >> 4, j16 = lane & 15;
    int half = lane >> 5, c = lane & 31, hh = c >> 3;
    float4 bv  = *(const float4*)(b1 + 4 * c);
    float4 u_s = *(const float4*)(usv + 4 * c);
    float4 u_d = *(const float4*)(udv + 4 * c);
    for (int i = wid; i < nNodes; i += 4) {
        int n = node0 + i;
        int dgi = deg[i] + 1;             // incl. self loop
        int st  = lsc[i] - dgi;
        float sd = sdst[n * 4 + h4];
        int s0 = elocal[st + ((j16 < dgi) ? j16 : 0)];
        float sraw = ssrc[s0 * 4 + h4];   // issue before shfl-dependent gathers
        uint2 pv[8];
        #pragma unroll
        for (int q = 0; q < 8; ++q) {
            int s = __shfl(s0, 2 * q + half);
            pv[q] = *(const uint2*)(h1b + (size_t)s * C1 + 4 * c);
        }
        float sv0 = (j16 < dgi) ? lrelu(sraw + sd) : -FLT_MAX;
        float mx = sv0;
        #pragma unroll
        for (int off = 1; off <= 8; off <<= 1) mx = fmaxf(mx, __shfl_xor(mx, off));
        for (int bb = 16; bb < dgi; bb += 16) {            // rare (deg>16)
            int j = bb + j16;
            float sv = -FLT_MAX;
            if (j < dgi) sv = lrelu(ssrc[elocal[st + j] * 4 + h4] + sd);
            #pragma unroll
            for (int off = 1; off <= 8; off <<= 1) sv = fmaxf(sv, __shfl_xor(sv, off));
            mx = fmaxf(mx, sv);
        }
        float w = (j16 < dgi) ? __expf(sv0 - mx) : 0.f;
        float den = w;
        float a0 = 0.f, a1 = 0.f, a2 = 0.f, a3 = 0.f;
        #pragma unroll
        for (int q = 0; q < 8; ++q) {
            float wq = __shfl(w, (hh << 4) + 2 * q + half);
            a0 = fmaf(wq, bflo(pv[q].x), a0);
            a1 = fmaf(wq, bfhi(pv[q].x), a1);
            a2 = fmaf(wq, bflo(pv[q].y), a2);
            a3 = fmaf(wq, bfhi(pv[q].y), a3);
        }
        for (int bb = 16; bb < dgi; bb += 16) {            // rare (deg>16)
            int j = bb + j16;
            int sreg = elocal[st + ((j < dgi) ? j : 0)];
            float wsr = ssrc[sreg * 4 + h4];
            uint2 qv[8];
            #pragma unroll
            for (int q = 0; q < 8; ++q) {
                int s = __shfl(sreg, 2 * q + half);
                qv[q] = *(const uint2*)(h1b + (size_t)s * C1 + 4 * c);
            }
            float wb = (j < dgi) ? __expf(lrelu(wsr + sd) - mx) : 0.f;
            den += wb;
            #pragma unroll
            for (int q = 0; q < 8; ++q) {
                float wq = __shfl(wb, (hh << 4) + 2 * q + half);
                a0 = fmaf(wq, bflo(qv[q].x), a0);
                a1 = fmaf(wq, bfhi(qv[q].x), a1);
                a2 = fmaf(wq, bflo(qv[q].y), a2);
                a3 = fmaf(wq, bfhi(qv[q].y), a3);
            }
        }
        #pragma unroll
        for (int off = 1; off <= 8; off <<= 1) den += __shfl_xor(den, off);
        float dh = __shfl(den, hh << 4);
        a0 += __shfl_xor(a0, 32);
        a1 += __shfl_xor(a1, 32);
        a2 += __shfl_xor(a2, 32);
        a3 += __shfl_xor(a3, 32);
        float rv = 1.f / dh;
        float v0 = fmaf(a0, rv, bv.x); v0 = v0 > 0.f ? v0 : 0.f;
        float v1 = fmaf(a1, rv, bv.y); v1 = v1 > 0.f ? v1 : 0.f;
        float v2 = fmaf(a2, rv, bv.z); v2 = v2 > 0.f ? v2 : 0.f;
        float v3 = fmaf(a3, rv, bv.w); v3 = v3 > 0.f ? v3 : 0.f;
        float ps = v0 * u_s.x + v1 * u_s.y + v2 * u_s.z + v3 * u_s.w;
        float pd = v0 * u_d.x + v1 * u_d.y + v2 * u_d.z + v3 * u_d.w;
        #pragma unroll
        for (int off = 1; off <= 16; off <<= 1) {
            ps += __shfl_xor(ps, off); pd += __shfl_xor(pd, off);
        }
        if (lane == 0) { ssrc2[n] = ps; sdst2[n] = pd; }
        if (half == 0) {
            ushort4 hs = make_ushort4(f2bf(v0), f2bf(v1), f2bf(v2), f2bf(v3));
            *reinterpret_cast<ushort4*>(hrb + (size_t)n * C1 + 4 * c) = hs;
        }
    }
}

// ============ GEMM2 (MFMA): h3 = hrb @ (W2@fcW), 128x64x128 per block ============
__global__ __launch_bounds__(256, 1) void k5_mfma(const u16* __restrict__ hrb,
    const u16* __restrict__ W2pbt, u16* __restrict__ h3b) {
    __shared__ u16 As[128][136];
    __shared__ u16 Bs[64][136];
    int t = threadIdx.x;
    int rbase = blockIdx.x * 128;
    #pragma unroll
    for (int j = 0; j < 4; ++j) {          // stage (W2@fcW)^T bf16
        int i = t + 256 * j, row = i >> 4, seg = i & 15;
        *reinterpret_cast<uint4*>(&Bs[row][seg * 8]) =
            *reinterpret_cast<const uint4*>(W2pbt + row * 128 + seg * 8);
    }
    #pragma unroll
    for (int j = 0; j < 8; ++j) {          // stage hrb tile (bf16, linear)
        int i = t + 256 * j, row = i >> 4, seg = i & 15;
        int gr = rbase + row; if (gr >= NN) gr = NN - 1;
        *reinterpret_cast<uint4*>(&As[row][seg * 8]) =
            *reinterpret_cast<const uint4*>(hrb + (size_t)gr * 128 + seg * 8);
    }
    __syncthreads();
    int lane = t & 63, wv = t >> 6, wr = wv >> 1, wc = wv & 1;
    int fr = lane & 15, fg = lane >> 4;
    f32x4 acc[4][2];
    #pragma unroll
    for (int m = 0; m < 4; ++m)
        #pragma unroll
        for (int n = 0; n < 2; ++n) acc[m][n] = (f32x4){0.f, 0.f, 0.f, 0.f};
    #pragma unroll
    for (int kk = 0; kk < 4; ++kk) {
        bf16x8 af[4], bfr[2];
        #pragma unroll
        for (int m = 0; m < 4; ++m)
            af[m] = *reinterpret_cast<const bf16x8*>(&As[wr * 64 + m * 16 + fr][kk * 32 + fg * 8]);
        #pragma unroll
        for (int n = 0; n < 2; ++n)
            bfr[n] = *reinterpret_cast<const bf16x8*>(&Bs[wc * 32 + n * 16 + fr][kk * 32 + fg * 8]);
        #pragma unroll
        for (int m = 0; m < 4; ++m)
            #pragma unroll
            for (int n = 0; n < 2; ++n)
                acc[m][n] = __builtin_amdgcn_mfma_f32_16x16x32_bf16(af[m], bfr[n], acc[m][n], 0, 0, 0);
    }
    #pragma unroll
    for (int m = 0; m < 4; ++m)
        #pragma unroll
        for (int r = 0; r < 4; ++r) {
            int row = rbase + wr * 64 + m * 16 + fg * 4 + r;
            if (row < NN) {
                #pragma unroll
                for (int n = 0; n < 2; ++n)
                    h3b[(size_t)row * 64 + wc * 32 + n * 16 + fr] = f2bf(acc[m][n][r]);
            }
        }
}

// ====== Aggregation layer 2 + log_softmax (FC pre-folded into h3) ======
__global__ __launch_bounds__(256) void agg2ls(const int* __restrict__ rowstart,
    const int* __restrict__ eidx, const float* __restrict__ ssrc,
    const float* __restrict__ sdst, const u16* __restrict__ h3b,
    const float* __restrict__ b2p, float* __restrict__ out) {
    int lane = threadIdx.x & 63;
    int n = blockIdx.x * 4 + (threadIdx.x >> 6);
    if (n >= NN) return;
    int r0 = rowstart[n], deg = rowstart[n + 1] - r0;
    int j16 = lane & 15, quarter = lane >> 4, c16 = lane & 15;
    float sd = sdst[n];
    int s0 = (j16 < deg) ? eidx[r0 + j16] : eidx[r0];
    float sraw = ssrc[s0];                 // issue before shfl-dependent gathers
    uint2 pv[4];
    #pragma unroll
    for (int q = 0; q < 4; ++q) {
        int s = __shfl(s0, 4 * q + quarter);
        pv[q] = *(const uint2*)(h3b + (size_t)s * C2 + 4 * c16);
    }
    float sv0 = (j16 < deg) ? lrelu(sraw + sd) : -FLT_MAX;
    float mx = sv0;
    #pragma unroll
    for (int off = 1; off <= 8; off <<= 1) mx = fmaxf(mx, __shfl_xor(mx, off));
    for (int base = 16; base < deg; base += 16) {            // rare
        int j = base + j16;
        float sv = -FLT_MAX;
        if (j < deg) sv = lrelu(ssrc[eidx[r0 + j]] + sd);
        #pragma unroll
        for (int off = 1; off <= 8; off <<= 1) sv = fmaxf(sv, __shfl_xor(sv, off));
        mx = fmaxf(mx, sv);
    }
    float w = (j16 < deg) ? __expf(sv0 - mx) : 0.f;
    float den = w;
    float a0 = 0.f, a1 = 0.f, a2 = 0.f, a3 = 0.f;
    #pragma unroll
    for (int q = 0; q < 4; ++q) {
        float wq = __shfl(w, 4 * q + quarter);
        a0 = fmaf(wq, bflo(pv[q].x), a0);
        a1 = fmaf(wq, bfhi(pv[q].x), a1);
        a2 = fmaf(wq, bflo(pv[q].y), a2);
        a3 = fmaf(wq, bfhi(pv[q].y), a3);
    }
    for (int base = 16; base < deg; base += 16) {            // rare
        int j = base + j16;
        int sreg = (j < deg) ? eidx[r0 + j] : eidx[r0];
        float wsr = ssrc[sreg];
        uint2 qv[4];
        #pragma unroll
        for (int q = 0; q < 4; ++q) {
            int s = __shfl(sreg, 4 * q + quarter);
            qv[q] = *(const uint2*)(h3b + (size_t)s * C2 + 4 * c16);
        }
        float wb = (j < deg) ? __expf(lrelu(wsr + sd) - mx) : 0.f;
        den += wb;
        #pragma unroll
        for (int q = 0; q < 4; ++q) {
            float wq = __shfl(wb, 4 * q + quarter);
            a0 = fmaf(wq, bflo(qv[q].x), a0);
            a1 = fmaf(wq, bfhi(qv[q].x), a1);
            a2 = fmaf(wq, bflo(qv[q].y), a2);
            a3 = fmaf(wq, bfhi(qv[q].y), a3);
        }
    }
    #pragma unroll
    for (int off = 1; off <= 8; off <<= 1) den += __shfl_xor(den, off);
    a0 += __shfl_xor(a0, 16); a0 += __shfl_xor(a0, 32);
    a1 += __shfl_xor(a1, 16); a1 += __shfl_xor(a1, 32);
    a2 += __shfl_xor(a2, 16); a2 += __shfl_xor(a2, 32);
    a3 += __shfl_xor(a3, 16); a3 += __shfl_xor(a3, 32);
    float4 bv = *(const float4*)(b2p + 4 * c16);
    float rd = 1.f / den;
    float v0 = a0 * rd + bv.x, v1 = a1 * rd + bv.y;
    float v2 = a2 * rd + bv.z, v3 = a3 * rd + bv.w;
    float m4 = fmaxf(fmaxf(v0, v1), fmaxf(v2, v3));
    #pragma unroll
    for (int off = 1; off <= 8; off <<= 1) m4 = fmaxf(m4, __shfl_xor(m4, off));
    float se = __expf(v0 - m4) + __expf(v1 - m4) + __expf(v2 - m4) + __expf(v3 - m4);
    #pragma unroll
    for (int off = 1; off <= 8; off <<= 1) se += __shfl_xor(se, off);
    float lse = m4 + logf(se);
    if (quarter == 0) {
        *(float4*)(out + (size_t)n * C2 + 4 * c16) =
            make_float4(v0 - lse, v1 - lse, v2 - lse, v3 - lse);
    }
}

extern "C" void kernel_launch(void* const* d_in, const int* in_sizes, int n_in,
                              void* d_out, int out_size, void* d_ws, size_t ws_size,
                              hipStream_t stream) {
    const float* x   = (const float*)d_in[0];
    const int*   ei  = (const int*)d_in[1];
    const float* W1  = (const float*)d_in[2];
    const float* as1 = (const float*)d_in[3];
    const float* ad1 = (const float*)d_in[4];
    const float* b1  = (const float*)d_in[5];
    const float* W2  = (const float*)d_in[6];
    const float* as2 = (const float*)d_in[7];
    const float* ad2 = (const float*)d_in[8];
    const float* b2  = (const float*)d_in[9];
    const float* fcW = (const float*)d_in[10];
    const float* fcb = (const float*)d_in[11];
    float* out = (float*)d_out;

    float* ws = (float*)d_ws;
    size_t o = 0;
    u16* h1b   = (u16*)(ws + o); o += (size_t)NN * C1 / 2;  // bf16 [NN][128] (reused as h3b)
    u16* hrb   = (u16*)(ws + o); o += (size_t)NN * C1 / 2;  // bf16 [NN][128]
    float* ssrc1 = ws + o; o += (size_t)NN * 4;
    float* sdst1 = ws + o; o += (size_t)NN * 4;
    float* ssrc2 = ws + o; o += NN;
    float* sdst2 = ws + o; o += NN;
    float* usv   = ws + o; o += 128;
    float* udv   = ws + o; o += 128;
    float* b2p   = ws + o; o += 64;
    u16* W2pbt = (u16*)(ws + o); o += 64 * 128 / 2;
    u16* W1bt  = (u16*)(ws + o); o += 128 * 128 / 2;
    int* ip = (int*)(ws + o);
    int* bcnt     = ip; ip += NBKT * 16;       // line-padded counters
    int* bbase    = ip; ip += 1024;
    int* rowstart = ip; ip += NN + 2;
    int* eidx     = ip; ip += TE;
    u32* bbuf     = (u32*)ip; ip += (size_t)NBKT * BCAP;   // 12.8 MB
    u16* h3b = h1b;   // h1b dead after agg1; reuse for h3

    const int* esrc = ei;
    const int* edst = ei + EE;

    hipMemsetAsync(bcnt, 0, (size_t)NBKT * 16 * sizeof(int), stream);

    // edge->bucket scatter + weight precompute (merged)
    kpassA<<<NPA + 259, 256, 0, stream>>>(esrc, edst, bcnt, bbuf,
                                          W2, as2, ad2, b2, fcW, fcb, W1,
                                          W2pbt, W1bt, usv, udv, b2p);
    kbscan<<<1, 1024, 0, stream>>>(bcnt, bbase);

    // layer 1 (scores fused into GEMM epilogue)
    k1_mfma<<<NB1, 256, 0, stream>>>(x, W1bt, as1, ad1, h1b, ssrc1, sdst1);
    // agg1 absorbs CSR finalize (kpassB) and emits rowstart/eidx for agg2ls
    agg1<<<NBKT, 256, 0, stream>>>(bcnt, bbase, bbuf, ssrc1, sdst1, h1b, b1,
                                   usv, udv, hrb, ssrc2, sdst2, rowstart, eidx);
    // layer 2 (FC pre-folded)
    k5_mfma<<<NB1, 256, 0, stream>>>(hrb, W2pbt, h3b);
    agg2ls<<<(NN + 3) / 4, 256, 0, stream>>>(rowstart, eidx, ssrc2, sdst2, h3b, b2p, out);
}

// Round 15
// 204.128 us; speedup vs baseline: 1.1844x; 1.0586x over previous
//
#include <hip/hip_runtime.h>
#include <hip/hip_bf16.h>
#include <cfloat>

#define NN 100000
#define EE 1000000
#define TE (EE + NN)   // edges incl. self loops
#define C1 128         // HEADS*HID
#define C2 64
#define NB1 782        // ceil(NN/128)
#define NBKT 782       // buckets of 128 dst nodes
#define BCAP 4096      // per-bucket edge capacity (expected ~1280)
#define BSLOT (BCAP + 128)   // fixed per-bucket eidx slot -> no scan kernel
#define NPA 977        // ceil((EE/4)/256) edge-scatter blocks

typedef unsigned short u16;
typedef unsigned int u32;
using bf16x8 = __attribute__((ext_vector_type(8))) short;
using f32x4  = __attribute__((ext_vector_type(4))) float;

__device__ __forceinline__ float lrelu(float v) { return v > 0.f ? v : 0.2f * v; }
__device__ __forceinline__ u16 f2bf(float f) {           // RNE f32 -> bf16 bits
    u32 b = __float_as_uint(f);
    b += 0x7fffu + ((b >> 16) & 1u);
    return (u16)(b >> 16);
}
__device__ __forceinline__ float bflo(u32 p) { return __uint_as_float(p << 16); }
__device__ __forceinline__ float bfhi(u32 p) { return __uint_as_float(p & 0xffff0000u); }

// ====== merged: edge->bucket scatter (blocks < NPA) + weight precompute ======
__global__ __launch_bounds__(256) void kpassA(const int* __restrict__ esrc,
    const int* __restrict__ edst, int* __restrict__ bcnt, u32* __restrict__ bbuf,
    const float* __restrict__ W2, const float* __restrict__ as2,
    const float* __restrict__ ad2, const float* __restrict__ b2,
    const float* __restrict__ fcW, const float* __restrict__ fcb,
    const float* __restrict__ W1, u16* __restrict__ W2pbt, u16* __restrict__ W1bt,
    float* __restrict__ us, float* __restrict__ ud, float* __restrict__ b2p) {
    int blk = blockIdx.x;
    if (blk < NPA) {
        int i = blk * 256 + threadIdx.x;
        if (i >= EE / 4) return;
        int4 s4 = ((const int4*)esrc)[i];
        int4 d4 = ((const int4*)edst)[i];
        int d, s, b, pos;
        d = d4.x; s = s4.x; b = d >> 7;
        pos = atomicAdd(bcnt + b * 16, 1);
        if (pos < BCAP) bbuf[(size_t)b * BCAP + pos] = (u32)s | ((u32)(d & 127) << 17);
        d = d4.y; s = s4.y; b = d >> 7;
        pos = atomicAdd(bcnt + b * 16, 1);
        if (pos < BCAP) bbuf[(size_t)b * BCAP + pos] = (u32)s | ((u32)(d & 127) << 17);
        d = d4.z; s = s4.z; b = d >> 7;
        pos = atomicAdd(bcnt + b * 16, 1);
        if (pos < BCAP) bbuf[(size_t)b * BCAP + pos] = (u32)s | ((u32)(d & 127) << 17);
        d = d4.w; s = s4.w; b = d >> 7;
        pos = atomicAdd(bcnt + b * 16, 1);
        if (pos < BCAP) bbuf[(size_t)b * BCAP + pos] = (u32)s | ((u32)(d & 127) << 17);
        return;
    }
    // ---- prep role ----
    int b = blk - NPA, t = threadIdx.x;
    if (t >= 64) return;
    if (b < 128) {                     // row b of W2p -> transposed bf16
        float s = 0.f;
        for (int k = 0; k < 64; ++k) s = fmaf(W2[b * 64 + k], fcW[k * 64 + t], s);
        W2pbt[t * 128 + b] = f2bf(s);
    } else if (b < 130) {
        int r = (b - 128) * 64 + t;
        float s = 0.f, d = 0.f;
        for (int k = 0; k < 64; ++k) {
            float wv = W2[r * 64 + k];
            s = fmaf(wv, as2[k], s);
            d = fmaf(wv, ad2[k], d);
        }
        us[r] = s; ud[r] = d;
    } else if (b == 130) {
        float s = fcb[t];
        for (int k = 0; k < 64; ++k) s = fmaf(b2[k], fcW[k * 64 + t], s);
        b2p[t] = s;
    } else {                           // b-131 = col c of W1 -> W1bt[c][k]
        int c = b - 131;
        W1bt[c * 128 + t]      = f2bf(W1[t * 128 + c]);
        W1bt[c * 128 + 64 + t] = f2bf(W1[(64 + t) * 128 + c]);
    }
}

// ====== CSR finalize per bucket; fixed base b*BSLOT; explicit degs array ======
__global__ __launch_bounds__(256) void kpassB(const int* __restrict__ bcnt,
    const u32* __restrict__ bbuf, int* __restrict__ rowstart,
    int* __restrict__ degs, int* __restrict__ eidx) {
    __shared__ int deg[128], lsc[128], cur[128];
    __shared__ int elocal[BCAP + 128];
    int b = blockIdx.x, t = threadIdx.x;
    int node0 = b * 128;
    int nNodes = NN - node0; if (nNodes > 128) nNodes = 128;
    int M = bcnt[b * 16]; if (M > BCAP) M = BCAP;
    int base = b * BSLOT;
    if (t < 128) deg[t] = 0;
    __syncthreads();
    const u32* bp = bbuf + (size_t)b * BCAP;
    for (int i = t; i < M; i += 256) atomicAdd(&deg[bp[i] >> 17], 1);
    __syncthreads();
    int v = 0;
    if (t < 128) { v = (t < nNodes) ? (1 + deg[t]) : 0; lsc[t] = v; }
    __syncthreads();
    for (int off = 1; off < 128; off <<= 1) {
        int o = 0;
        if (t < 128 && t >= off) o = lsc[t - off];
        __syncthreads();
        if (t < 128 && t >= off) lsc[t] += o;
        __syncthreads();
    }
    if (t < nNodes) {
        int st = lsc[t] - v;              // exclusive
        rowstart[node0 + t] = base + st;
        degs[node0 + t] = v;              // deg incl. self loop
        elocal[st] = node0 + t;           // self loop in slot 0
        cur[t] = st + 1;
    }
    __syncthreads();
    for (int i = t; i < M; i += 256) {
        u32 p = bp[i];
        int pos = atomicAdd(&cur[p >> 17], 1);
        elocal[pos] = (int)(p & 0x1FFFFu);
    }
    __syncthreads();
    int total = M + nNodes;
    for (int i = t; i < total; i += 256) eidx[base + i] = elocal[i];
}

// ============ GEMM1 (MFMA): h1 = x @ W1, 128x128x128 per block ============
__global__ __launch_bounds__(256, 1) void k1_mfma(const float* __restrict__ x,
    const u16* __restrict__ W1bt, u16* __restrict__ h1b) {
    __shared__ u16 As[128][136];   // A[row][k], +8 pad
    __shared__ u16 Bs[128][136];   // B^T: [col][k]
    int t = threadIdx.x;
    int rbase = blockIdx.x * 128;
    #pragma unroll
    for (int j = 0; j < 8; ++j) {          // stage W1^T (bf16, linear)
        int i = t + 256 * j, row = i >> 4, seg = i & 15;
        *reinterpret_cast<uint4*>(&Bs[row][seg * 8]) =
            *reinterpret_cast<const uint4*>(W1bt + row * 128 + seg * 8);
    }
    #pragma unroll
    for (int j = 0; j < 16; ++j) {         // stage x tile, fp32->bf16
        int i = t + 256 * j, row = i >> 5, c4 = i & 31;
        int gr = rbase + row; if (gr >= NN) gr = NN - 1;
        float4 v = *reinterpret_cast<const float4*>(x + (size_t)gr * 128 + c4 * 4);
        ushort4 o2 = make_ushort4(f2bf(v.x), f2bf(v.y), f2bf(v.z), f2bf(v.w));
        *reinterpret_cast<ushort4*>(&As[row][c4 * 4]) = o2;
    }
    __syncthreads();
    int lane = t & 63, wv = t >> 6, wr = wv >> 1, wc = wv & 1;
    int fr = lane & 15, fg = lane >> 4;
    f32x4 acc[4][4];
    #pragma unroll
    for (int m = 0; m < 4; ++m)
        #pragma unroll
        for (int n = 0; n < 4; ++n) acc[m][n] = (f32x4){0.f, 0.f, 0.f, 0.f};
    #pragma unroll
    for (int kk = 0; kk < 4; ++kk) {
        bf16x8 af[4], bfr[4];
        #pragma unroll
        for (int m = 0; m < 4; ++m)
            af[m] = *reinterpret_cast<const bf16x8*>(&As[wr * 64 + m * 16 + fr][kk * 32 + fg * 8]);
        #pragma unroll
        for (int n = 0; n < 4; ++n)
            bfr[n] = *reinterpret_cast<const bf16x8*>(&Bs[wc * 64 + n * 16 + fr][kk * 32 + fg * 8]);
        #pragma unroll
        for (int m = 0; m < 4; ++m)
            #pragma unroll
            for (int n = 0; n < 4; ++n)
                acc[m][n] = __builtin_amdgcn_mfma_f32_16x16x32_bf16(af[m], bfr[n], acc[m][n], 0, 0, 0);
    }
    #pragma unroll
    for (int m = 0; m < 4; ++m)
        #pragma unroll
        for (int r = 0; r < 4; ++r) {
            int row = rbase + wr * 64 + m * 16 + fg * 4 + r;
            if (row < NN) {
                #pragma unroll
                for (int n = 0; n < 4; ++n)
                    h1b[(size_t)row * 128 + wc * 64 + n * 16 + fr] = f2bf(acc[m][n][r]);
            }
        }
}

// ======== layer-1 attention scores from h1b (4 heads x 32 ch) ========
__global__ __launch_bounds__(256) void kscore1(const u16* __restrict__ h1b,
    const float* __restrict__ as1, const float* __restrict__ ad1,
    float* __restrict__ ssrc, float* __restrict__ sdst) {
    __shared__ float asl[128], adl[128];
    if (threadIdx.x < 128) { asl[threadIdx.x] = as1[threadIdx.x]; adl[threadIdx.x] = ad1[threadIdx.x]; }
    __syncthreads();
    int g = blockIdx.x * 256 + threadIdx.x;
    if (g >= NN * 4) return;
    int row = g >> 2, h = g & 3;
    const u16* hp = h1b + (size_t)row * 128 + h * 32;
    float ps = 0.f, pd = 0.f;
    #pragma unroll
    for (int q = 0; q < 4; ++q) {
        uint4 pk = *reinterpret_cast<const uint4*>(hp + q * 8);
        u32 wsv[4] = {pk.x, pk.y, pk.z, pk.w};
        #pragma unroll
        for (int e = 0; e < 4; ++e) {
            int c = h * 32 + q * 8 + e * 2;
            float lo = bflo(wsv[e]), hi = bfhi(wsv[e]);
            ps = fmaf(lo, asl[c], ps); ps = fmaf(hi, asl[c + 1], ps);
            pd = fmaf(lo, adl[c], pd); pd = fmaf(hi, adl[c + 1], pd);
        }
    }
    ssrc[g] = ps;
    sdst[g] = pd;
}

// ====== Aggregation layer 1 + layer-2 scores; writes bf16 hrb (R10 form) ======
__global__ __launch_bounds__(256) void agg1(const int* __restrict__ rowstart,
    const int* __restrict__ degs, const int* __restrict__ eidx,
    const float* __restrict__ ssrc, const float* __restrict__ sdst,
    const u16* __restrict__ h1b, const float* __restrict__ b1,
    const float* __restrict__ usv, const float* __restrict__ udv,
    u16* __restrict__ hrb, float* __restrict__ ssrc2, float* __restrict__ sdst2) {
    int lane = threadIdx.x & 63;
    int n = blockIdx.x * 4 + (threadIdx.x >> 6);
    if (n >= NN) return;
    int r0 = rowstart[n], deg = degs[n];
    int h4 = lane >> 4, j16 = lane & 15;
    int half = lane >> 5, c = lane & 31, hh = c >> 3;
    float sd = sdst[n * 4 + h4];
    int s0 = (j16 < deg) ? eidx[r0 + j16] : eidx[r0];
    uint2 pv[8];
    #pragma unroll
    for (int q = 0; q < 8; ++q) {
        int s = __shfl(s0, 2 * q + half);
        pv[q] = *(const uint2*)(h1b + (size_t)s * C1 + 4 * c);
    }
    float sv0 = (j16 < deg) ? lrelu(ssrc[s0 * 4 + h4] + sd) : -FLT_MAX;
    float mx = sv0;
    #pragma unroll
    for (int off = 1; off <= 8; off <<= 1) mx = fmaxf(mx, __shfl_xor(mx, off));
    for (int base = 16; base < deg; base += 16) {            // rare (deg>16)
        int j = base + j16;
        float sv = (j < deg) ? lrelu(ssrc[eidx[r0 + j] * 4 + h4] + sd) : -FLT_MAX;
        #pragma unroll
        for (int off = 1; off <= 8; off <<= 1) sv = fmaxf(sv, __shfl_xor(sv, off));
        mx = fmaxf(mx, sv);
    }
    float w = (j16 < deg) ? __expf(sv0 - mx) : 0.f;
    float den = w;
    float a0 = 0.f, a1 = 0.f, a2 = 0.f, a3 = 0.f;
    #pragma unroll
    for (int q = 0; q < 8; ++q) {
        float wq = __shfl(w, (hh << 4) + 2 * q + half);
        a0 = fmaf(wq, bflo(pv[q].x), a0);
        a1 = fmaf(wq, bfhi(pv[q].x), a1);
        a2 = fmaf(wq, bflo(pv[q].y), a2);
        a3 = fmaf(wq, bfhi(pv[q].y), a3);
    }
    for (int base = 16; base < deg; base += 16) {            // rare (deg>16)
        int j = base + j16;
        int sreg = (j < deg) ? eidx[r0 + j] : eidx[r0];
        uint2 qv[8];
        #pragma unroll
        for (int q = 0; q < 8; ++q) {
            int s = __shfl(sreg, 2 * q + half);
            qv[q] = *(const uint2*)(h1b + (size_t)s * C1 + 4 * c);
        }
        float wb = (j < deg) ? __expf(lrelu(ssrc[sreg * 4 + h4] + sd) - mx) : 0.f;
        den += wb;
        #pragma unroll
        for (int q = 0; q < 8; ++q) {
            float wq = __shfl(wb, (hh << 4) + 2 * q + half);
            a0 = fmaf(wq, bflo(qv[q].x), a0);
            a1 = fmaf(wq, bfhi(qv[q].x), a1);
            a2 = fmaf(wq, bflo(qv[q].y), a2);
            a3 = fmaf(wq, bfhi(qv[q].y), a3);
        }
    }
    #pragma unroll
    for (int off = 1; off <= 8; off <<= 1) den += __shfl_xor(den, off);
    float dh = __shfl(den, hh << 4);
    a0 += __shfl_xor(a0, 32);
    a1 += __shfl_xor(a1, 32);
    a2 += __shfl_xor(a2, 32);
    a3 += __shfl_xor(a3, 32);
    float4 bv = *(const float4*)(b1 + 4 * c);
    float rv = 1.f / dh;
    float v0 = fmaf(a0, rv, bv.x); v0 = v0 > 0.f ? v0 : 0.f;
    float v1 = fmaf(a1, rv, bv.y); v1 = v1 > 0.f ? v1 : 0.f;
    float v2 = fmaf(a2, rv, bv.z); v2 = v2 > 0.f ? v2 : 0.f;
    float v3 = fmaf(a3, rv, bv.w); v3 = v3 > 0.f ? v3 : 0.f;
    // layer-2 scores: dot(relu_h, us/ud) over 128 channels (32-lane reduce)
    float4 u_s = *(const float4*)(usv + 4 * c);
    float4 u_d = *(const float4*)(udv + 4 * c);
    float ps = v0 * u_s.x + v1 * u_s.y + v2 * u_s.z + v3 * u_s.w;
    float pd = v0 * u_d.x + v1 * u_d.y + v2 * u_d.z + v3 * u_d.w;
    #pragma unroll
    for (int off = 1; off <= 16; off <<= 1) {
        ps += __shfl_xor(ps, off); pd += __shfl_xor(pd, off);
    }
    if (lane == 0) { ssrc2[n] = ps; sdst2[n] = pd; }
    if (half == 0) {
        ushort4 hs = make_ushort4(f2bf(v0), f2bf(v1), f2bf(v2), f2bf(v3));
        *reinterpret_cast<ushort4*>(hrb + (size_t)n * C1 + 4 * c) = hs;
    }
}

// ============ GEMM2 (MFMA): h3 = hrb @ (W2@fcW), 128x64x128 per block ============
__global__ __launch_bounds__(256, 1) void k5_mfma(const u16* __restrict__ hrb,
    const u16* __restrict__ W2pbt, u16* __restrict__ h3b) {
    __shared__ u16 As[128][136];
    __shared__ u16 Bs[64][136];
    int t = threadIdx.x;
    int rbase = blockIdx.x * 128;
    #pragma unroll
    for (int j = 0; j < 4; ++j) {          // stage (W2@fcW)^T bf16
        int i = t + 256 * j, row = i >> 4, seg = i & 15;
        *reinterpret_cast<uint4*>(&Bs[row][seg * 8]) =
            *reinterpret_cast<const uint4*>(W2pbt + row * 128 + seg * 8);
    }
    #pragma unroll
    for (int j = 0; j < 8; ++j) {          // stage hrb tile (bf16, linear)
        int i = t + 256 * j, row = i >> 4, seg = i & 15;
        int gr = rbase + row; if (gr >= NN) gr = NN - 1;
        *reinterpret_cast<uint4*>(&As[row][seg * 8]) =
            *reinterpret_cast<const uint4*>(hrb + (size_t)gr * 128 + seg * 8);
    }
    __syncthreads();
    int lane = t & 63, wv = t >> 6, wr = wv >> 1, wc = wv & 1;
    int fr = lane & 15, fg = lane >> 4;
    f32x4 acc[4][2];
    #pragma unroll
    for (int m = 0; m < 4; ++m)
        #pragma unroll
        for (int n = 0; n < 2; ++n) acc[m][n] = (f32x4){0.f, 0.f, 0.f, 0.f};
    #pragma unroll
    for (int kk = 0; kk < 4; ++kk) {
        bf16x8 af[4], bfr[2];
        #pragma unroll
        for (int m = 0; m < 4; ++m)
            af[m] = *reinterpret_cast<const bf16x8*>(&As[wr * 64 + m * 16 + fr][kk * 32 + fg * 8]);
        #pragma unroll
        for (int n = 0; n < 2; ++n)
            bfr[n] = *reinterpret_cast<const bf16x8*>(&Bs[wc * 32 + n * 16 + fr][kk * 32 + fg * 8]);
        #pragma unroll
        for (int m = 0; m < 4; ++m)
            #pragma unroll
            for (int n = 0; n < 2; ++n)
                acc[m][n] = __builtin_amdgcn_mfma_f32_16x16x32_bf16(af[m], bfr[n], acc[m][n], 0, 0, 0);
    }
    #pragma unroll
    for (int m = 0; m < 4; ++m)
        #pragma unroll
        for (int r = 0; r < 4; ++r) {
            int row = rbase + wr * 64 + m * 16 + fg * 4 + r;
            if (row < NN) {
                #pragma unroll
                for (int n = 0; n < 2; ++n)
                    h3b[(size_t)row * 64 + wc * 32 + n * 16 + fr] = f2bf(acc[m][n][r]);
            }
        }
}

// ====== Aggregation layer 2 + log_softmax (FC pre-folded into h3) ======
__global__ __launch_bounds__(256) void agg2ls(const int* __restrict__ rowstart,
    const int* __restrict__ degs, const int* __restrict__ eidx,
    const float* __restrict__ ssrc, const float* __restrict__ sdst,
    const u16* __restrict__ h3b, const float* __restrict__ b2p,
    float* __restrict__ out) {
    int lane = threadIdx.x & 63;
    int n = blockIdx.x * 4 + (threadIdx.x >> 6);
    if (n >= NN) return;
    int r0 = rowstart[n], deg = degs[n];
    int j16 = lane & 15, quarter = lane >> 4, c16 = lane & 15;
    float sd = sdst[n];
    int s0 = (j16 < deg) ? eidx[r0 + j16] : eidx[r0];
    float sraw = ssrc[s0];                 // issue before shfl-dependent gathers
    uint2 pv[4];
    #pragma unroll
    for (int q = 0; q < 4; ++q) {
        int s = __shfl(s0, 4 * q + quarter);
        pv[q] = *(const uint2*)(h3b + (size_t)s * C2 + 4 * c16);
    }
    float sv0 = (j16 < deg) ? lrelu(sraw + sd) : -FLT_MAX;
    float mx = sv0;
    #pragma unroll
    for (int off = 1; off <= 8; off <<= 1) mx = fmaxf(mx, __shfl_xor(mx, off));
    for (int base = 16; base < deg; base += 16) {            // rare
        int j = base + j16;
        float sv = -FLT_MAX;
        if (j < deg) sv = lrelu(ssrc[eidx[r0 + j]] + sd);
        #pragma unroll
        for (int off = 1; off <= 8; off <<= 1) sv = fmaxf(sv, __shfl_xor(sv, off));
        mx = fmaxf(mx, sv);
    }
    float w = (j16 < deg) ? __expf(sv0 - mx) : 0.f;
    float den = w;
    float a0 = 0.f, a1 = 0.f, a2 = 0.f, a3 = 0.f;
    #pragma unroll
    for (int q = 0; q < 4; ++q) {
        float wq = __shfl(w, 4 * q + quarter);
        a0 = fmaf(wq, bflo(pv[q].x), a0);
        a1 = fmaf(wq, bfhi(pv[q].x), a1);
        a2 = fmaf(wq, bflo(pv[q].y), a2);
        a3 = fmaf(wq, bfhi(pv[q].y), a3);
    }
    for (int base = 16; base < deg; base += 16) {            // rare
        int j = base + j16;
        int sreg = (j < deg) ? eidx[r0 + j] : eidx[r0];
        float wsr = ssrc[sreg];
        uint2 qv[4];
        #pragma unroll
        for (int q = 0; q < 4; ++q) {
            int s = __shfl(sreg, 4 * q + quarter);
            qv[q] = *(const uint2*)(h3b + (size_t)s * C2 + 4 * c16);
        }
        float wb = (j < deg) ? __expf(lrelu(wsr + sd) - mx) : 0.f;
        den += wb;
        #pragma unroll
        for (int q = 0; q < 4; ++q) {
            float wq = __shfl(wb, 4 * q + quarter);
            a0 = fmaf(wq, bflo(qv[q].x), a0);
            a1 = fmaf(wq, bfhi(qv[q].x), a1);
            a2 = fmaf(wq, bflo(qv[q].y), a2);
            a3 = fmaf(wq, bfhi(qv[q].y), a3);
        }
    }
    #pragma unroll
    for (int off = 1; off <= 8; off <<= 1) den += __shfl_xor(den, off);
    a0 += __shfl_xor(a0, 16); a0 += __shfl_xor(a0, 32);
    a1 += __shfl_xor(a1, 16); a1 += __shfl_xor(a1, 32);
    a2 += __shfl_xor(a2, 16); a2 += __shfl_xor(a2, 32);
    a3 += __shfl_xor(a3, 16); a3 += __shfl_xor(a3, 32);
    float4 bv = *(const float4*)(b2p + 4 * c16);
    float rd = 1.f / den;
    float v0 = a0 * rd + bv.x, v1 = a1 * rd + bv.y;
    float v2 = a2 * rd + bv.z, v3 = a3 * rd + bv.w;
    float m4 = fmaxf(fmaxf(v0, v1), fmaxf(v2, v3));
    #pragma unroll
    for (int off = 1; off <= 8; off <<= 1) m4 = fmaxf(m4, __shfl_xor(m4, off));
    float se = __expf(v0 - m4) + __expf(v1 - m4) + __expf(v2 - m4) + __expf(v3 - m4);
    #pragma unroll
    for (int off = 1; off <= 8; off <<= 1) se += __shfl_xor(se, off);
    float lse = m4 + logf(se);
    if (quarter == 0) {
        *(float4*)(out + (size_t)n * C2 + 4 * c16) =
            make_float4(v0 - lse, v1 - lse, v2 - lse, v3 - lse);
    }
}

extern "C" void kernel_launch(void* const* d_in, const int* in_sizes, int n_in,
                              void* d_out, int out_size, void* d_ws, size_t ws_size,
                              hipStream_t stream) {
    const float* x   = (const float*)d_in[0];
    const int*   ei  = (const int*)d_in[1];
    const float* W1  = (const float*)d_in[2];
    const float* as1 = (const float*)d_in[3];
    const float* ad1 = (const float*)d_in[4];
    const float* b1  = (const float*)d_in[5];
    const float* W2  = (const float*)d_in[6];
    const float* as2 = (const float*)d_in[7];
    const float* ad2 = (const float*)d_in[8];
    const float* b2  = (const float*)d_in[9];
    const float* fcW = (const float*)d_in[10];
    const float* fcb = (const float*)d_in[11];
    float* out = (float*)d_out;

    float* ws = (float*)d_ws;
    size_t o = 0;
    u16* h1b   = (u16*)(ws + o); o += (size_t)NN * C1 / 2;  // bf16 [NN][128] (reused as h3b)
    u16* hrb   = (u16*)(ws + o); o += (size_t)NN * C1 / 2;  // bf16 [NN][128]
    float* ssrc1 = ws + o; o += (size_t)NN * 4;
    float* sdst1 = ws + o; o += (size_t)NN * 4;
    float* ssrc2 = ws + o; o += NN;
    float* sdst2 = ws + o; o += NN;
    float* usv   = ws + o; o += 128;
    float* udv   = ws + o; o += 128;
    float* b2p   = ws + o; o += 64;
    u16* W2pbt = (u16*)(ws + o); o += 64 * 128 / 2;
    u16* W1bt  = (u16*)(ws + o); o += 128 * 128 / 2;
    int* ip = (int*)(ws + o);
    int* bcnt     = ip; ip += NBKT * 16;       // line-padded counters
    int* rowstart = ip; ip += NN + 2;
    int* degs     = ip; ip += NN;
    int* eidx     = ip; ip += (size_t)NBKT * BSLOT;        // fixed-slot layout, 13.2 MB
    u32* bbuf     = (u32*)ip; ip += (size_t)NBKT * BCAP;   // 12.8 MB
    u16* h3b = h1b;   // h1b dead after agg1; reuse for h3

    const int* esrc = ei;
    const int* edst = ei + EE;

    hipMemsetAsync(bcnt, 0, (size_t)NBKT * 16 * sizeof(int), stream);

    // edge->bucket scatter + weight precompute (merged)
    kpassA<<<NPA + 259, 256, 0, stream>>>(esrc, edst, bcnt, bbuf,
                                          W2, as2, ad2, b2, fcW, fcb, W1,
                                          W2pbt, W1bt, usv, udv, b2p);
    // CSR finalize (fixed bucket bases; explicit per-node degree array)
    kpassB<<<NBKT, 256, 0, stream>>>(bcnt, bbuf, rowstart, degs, eidx);

    // layer 1
    k1_mfma<<<NB1, 256, 0, stream>>>(x, W1bt, h1b);
    kscore1<<<(NN * 4 + 255) / 256, 256, 0, stream>>>(h1b, as1, ad1, ssrc1, sdst1);
    agg1<<<(NN + 3) / 4, 256, 0, stream>>>(rowstart, degs, eidx, ssrc1, sdst1, h1b,
                                           b1, usv, udv, hrb, ssrc2, sdst2);
    // layer 2 (FC pre-folded)
    k5_mfma<<<NB1, 256, 0, stream>>>(hrb, W2pbt, h3b);
    agg2ls<<<(NN + 3) / 4, 256, 0, stream>>>(rowstart, degs, eidx, ssrc2, sdst2,
                                             h3b, b2p, out);
}